// Round 6
// baseline (2027.490 us; speedup 1.0000x reference)
//
#include <hip/hip_runtime.h>
#include <hip/hip_bf16.h>

#define NN 50000
#define NE 800000

typedef __bf16 bf16x8 __attribute__((ext_vector_type(8)));
typedef float f4v __attribute__((ext_vector_type(4)));

__device__ __forceinline__ float silu_f(float v){ return v/(1.0f+__expf(-v)); }
__device__ __forceinline__ float bf2f(unsigned int u){ return __uint_as_float(u<<16); }
__device__ __forceinline__ unsigned short f2bf(float f){ __hip_bfloat16 b=__float2bfloat16(f); return *reinterpret_cast<unsigned short*>(&b); }
__device__ __forceinline__ unsigned pk2(float a, float b){ return (unsigned)f2bf(a) | ((unsigned)f2bf(b)<<16); }

union U8 { unsigned short us[8]; uint4 u4; };

__device__ __forceinline__ void pack8(unsigned short* dst, float4 a, float4 b){
  uint4 u;
  u.x = pk2(a.x,a.y); u.y = pk2(a.z,a.w);
  u.z = pk2(b.x,b.y); u.w = pk2(b.z,b.w);
  *(uint4*)dst = u;
}
__device__ __forceinline__ void unpack8(uint4 u, float* f){
  f[0]=bf2f(u.x&0xffffu); f[1]=bf2f(u.x>>16);
  f[2]=bf2f(u.y&0xffffu); f[3]=bf2f(u.y>>16);
  f[4]=bf2f(u.z&0xffffu); f[5]=bf2f(u.z>>16);
  f[6]=bf2f(u.w&0xffffu); f[7]=bf2f(u.w>>16);
}

// short-index of 16B chunk c of row e in a row-major swizzled activation buffer
// (CH = chunks per row, multiple of 8; chunk swizzled within its group of 8)
__device__ __forceinline__ int lidx(int e, int c, int CH){
  return (e*CH + ((c & ~7) | ((c ^ e) & 7))) << 3;
}

// GEMM: A = weights (global frag order), B = activations (row-major swizzled LDS).
// acc[et][ot]: D rows = outcols (wu*32+ot*16+quad*4+r), cols = edges (et*16+(lane&15)).
template<int KC, int CH>
__device__ __forceinline__ void gemm_rm(const unsigned short* act, const unsigned short* wf,
                                        int wu, int lane, f4v (&acc)[4][2]){
  int le = lane & 15, quad = lane >> 4;
  #pragma unroll
  for (int kc=0;kc<KC;kc++){
    bf16x8 a0 = *(const bf16x8*)(wf + (((wu*2  )*KC + kc)<<9) + lane*8);
    bf16x8 a1 = *(const bf16x8*)(wf + (((wu*2+1)*KC + kc)<<9) + lane*8);
    int chunk = kc*4 + quad;
    #pragma unroll
    for (int et=0;et<4;et++){
      bf16x8 b = *(const bf16x8*)(act + lidx(et*16+le, chunk, CH));
      acc[et][0] = __builtin_amdgcn_mfma_f32_16x16x32_bf16(a0, b, acc[et][0], 0,0,0);
      acc[et][1] = __builtin_amdgcn_mfma_f32_16x16x32_bf16(a1, b, acc[et][1], 0,0,0);
    }
  }
}

// epilogue: D regs -> row-major swizzled bf16 buffer, packed b64 stores
template<int CH, bool SILU, bool BIAS>
__device__ __forceinline__ void epi_rm(unsigned short* dst, const f4v (&acc)[4][2],
                                       const float* bias, int wu, int lane){
  int le = lane & 15, quad = lane >> 4;
  #pragma unroll
  for (int ot=0; ot<2; ot++){
    float4 bv = make_float4(0,0,0,0);
    if (BIAS) bv = *(const float4*)(bias + wu*32 + ot*16 + quad*4);
    int chunk = wu*4 + ot*2 + (quad>>1);
    int soff = (quad&1)*4;
    #pragma unroll
    for (int et=0; et<4; et++){
      float v0=acc[et][ot][0], v1=acc[et][ot][1], v2=acc[et][ot][2], v3=acc[et][ot][3];
      if (BIAS){ v0+=bv.x; v1+=bv.y; v2+=bv.z; v3+=bv.w; }
      if (SILU){ v0=silu_f(v0); v1=silu_f(v1); v2=silu_f(v2); v3=silu_f(v3); }
      uint2 u; u.x = pk2(v0,v1); u.y = pk2(v2,v3);
      *(uint2*)(dst + lidx(et*16+le, chunk, CH) + soff) = u;
    }
  }
}

// per-edge (lane = edge) PARTIAL dot: wave wu covers cols wu*32..wu*32+31
// (chunks wu*4..wu*4+3); the 4 waves' atomicAdds compose the full 128-dot.
template<int CH>
__device__ __forceinline__ void dot4(const unsigned short* buf, int wu, int lane,
                                     const float* __restrict__ W, float* p){
  float p0=0,p1=0,p2=0,p3=0;
  #pragma unroll
  for (int cc=0;cc<4;cc++){
    int c = wu*4 + cc;
    uint4 u = *(const uint4*)(buf + lidx(lane, c, CH));
    float f[8]; unpack8(u,f);
    #pragma unroll
    for (int j=0;j<8;j++){
      const float4 w4 = *(const float4*)(W + (c*8+j)*4);
      p0+=f[j]*w4.x; p1+=f[j]*w4.y; p2+=f[j]*w4.z; p3+=f[j]*w4.w;
    }
  }
  p[0]=p0; p[1]=p1; p[2]=p2; p[3]=p3;
}

// ---------------- zero a span ----------------
__global__ __launch_bounds__(256) void k_zero(float* __restrict__ p, int n){
  int i = blockIdx.x*256 + threadIdx.x;
  if (i < n) p[i] = 0.f;
}

// ---------------- weight pre-pack into MFMA fragment order (bf16) ----------------
__global__ __launch_bounds__(256) void k_wprep(const float* __restrict__ src, unsigned short* __restrict__ dst,
                                               int Kreal, int KC){
  int idx = blockIdx.x*256 + threadIdx.x;
  int tot = 8*KC*512;
  if (idx >= tot) return;
  int nt  = idx/(KC*512); int rem = idx%(KC*512);
  int kc  = rem>>9;       int r2  = rem&511;
  int lq  = r2>>3;        int j   = r2&7;
  int k   = kc*32 + (lq>>4)*8 + j;
  int n   = nt*16 + (lq&15);
  float v = (k < Kreal) ? src[k*128 + n] : 0.f;
  dst[idx] = f2bf(v);
}

// ---------------- stats ----------------
__global__ __launch_bounds__(256) void k_stats(const float* __restrict__ x, float* __restrict__ stats){
  int i = blockIdx.x*256 + threadIdx.x;
  float v0=0.f,v1=0.f,v2=0.f;
  if (i < NN){ v0=x[i*3+0]; v1=x[i*3+1]; v2=x[i*3+2]; }
  float vals[6] = {v0,v1,v2,v0*v0,v1*v1,v2*v2};
  __shared__ float red[256];
  for (int c=0;c<6;c++){
    red[threadIdx.x]=vals[c];
    __syncthreads();
    for (int off=128; off>0; off>>=1){
      if (threadIdx.x < off) red[threadIdx.x] += red[threadIdx.x+off];
      __syncthreads();
    }
    if (threadIdx.x==0) atomicAdd(&stats[c], red[0]);
    __syncthreads();
  }
}

__global__ __launch_bounds__(64) void k_statsfin(float* __restrict__ stats){
  int t = threadIdx.x;
  if (t < 3){
    float s = stats[t], sq = stats[3+t];
    float mean = s/(float)NN;
    float var = (sq - s*s/(float)NN)/(float)(NN-1);
    float sd = sqrtf(var);
    stats[6+t] = mean;
    stats[9+t] = 1.0f/(sd + 1e-8f);
  }
}

// ---------------- q,k,v = h @ W + b  (bf16 out; v stored [node][d][head]) ----------------
__global__ __launch_bounds__(256) void k_qkv(const float* __restrict__ h,
    const float* __restrict__ Wq, const float* __restrict__ bq,
    const float* __restrict__ Wk, const float* __restrict__ bk,
    const float* __restrict__ Wv, const float* __restrict__ bv,
    unsigned short* __restrict__ q, unsigned short* __restrict__ kk, unsigned short* __restrict__ v){
  __shared__ float hs[32*68];
  int t = threadIdx.x;
  int by = blockIdx.y;
  int mat = by>>2; int quarter = by&3; int colbase = quarter*64;
  const float* W; const float* bb; unsigned short* outp;
  if (mat==0){W=Wq;bb=bq;outp=q;} else if (mat==1){W=Wk;bb=bk;outp=kk;} else {W=Wv;bb=bv;outp=v;}
  int r0 = blockIdx.x*32;
  {
    int rw = t>>3; int c0 = (t&7)*8;
    int row = r0 + rw;
    float4 a = make_float4(0,0,0,0), b2 = make_float4(0,0,0,0);
    if (row < NN){
      a  = *(const float4*)(h + (size_t)row*64 + c0);
      b2 = *(const float4*)(h + (size_t)row*64 + c0 + 4);
    }
    *(float4*)(&hs[rw*68 + c0])     = a;
    *(float4*)(&hs[rw*68 + c0 + 4]) = b2;
  }
  __syncthreads();
  int rg = t>>3; int cg = t&7; int col = colbase + cg*8;
  float acc[8];
  #pragma unroll
  for (int j=0;j<8;j++) acc[j]=0.f;
  for (int k2=0;k2<64;k2++){
    float a = hs[rg*68 + k2];
    const float4 w0 = *(const float4*)(W + k2*256 + col);
    const float4 w1 = *(const float4*)(W + k2*256 + col + 4);
    acc[0]+=a*w0.x; acc[1]+=a*w0.y; acc[2]+=a*w0.z; acc[3]+=a*w0.w;
    acc[4]+=a*w1.x; acc[5]+=a*w1.y; acc[6]+=a*w1.z; acc[7]+=a*w1.w;
  }
  int row = r0 + rg;
  if (row < NN){
    if (mat==2){
      #pragma unroll
      for (int j=0;j<8;j++) outp[(size_t)row*256 + (size_t)(cg*8+j)*4 + quarter] = f2bf(acc[j]+bb[col+j]);
    } else {
      U8 u;
      #pragma unroll
      for (int j=0;j<8;j++) u.us[j] = f2bf(acc[j]+bb[col+j]);
      *(uint4*)(outp + (size_t)row*256 + col) = u.u4;
    }
  }
}

// ---------------- CSR build ----------------
__global__ __launch_bounds__(256) void k_count(const int* __restrict__ ei, int* __restrict__ counts){
  int e = blockIdx.x*256 + threadIdx.x;
  if (e < NE) atomicAdd(&counts[ei[e]], 1);
}

__global__ __launch_bounds__(256) void k_scan(int* __restrict__ counts, int* __restrict__ offs){
  __shared__ int ps[256];
  int t = threadIdx.x;
  int base = t*196;
  int s = 0;
  for (int i=0;i<196;i++){ int idx = base+i; if (idx < NN) s += counts[idx]; }
  ps[t]=s; __syncthreads();
  for (int off=1; off<256; off<<=1){
    int vv = (t>=off)? ps[t-off] : 0;
    __syncthreads();
    ps[t]+=vv;
    __syncthreads();
  }
  int run = ps[t]-s;
  for (int i=0;i<196;i++){
    int idx = base+i;
    if (idx < NN){ int c = counts[idx]; offs[idx]=run; counts[idx]=run; run+=c; }
  }
  if (t==255) offs[NN]=run;
}

__global__ __launch_bounds__(256) void k_fill(const int* __restrict__ ei, int* __restrict__ cursor, int* __restrict__ elist){
  int e = blockIdx.x*256 + threadIdx.x;
  if (e < NE){
    int r = ei[e];
    int p = atomicAdd(&cursor[r],1);
    elist[p] = e;
  }
}

// ---------------- E1: edge MLP (MFMA, row-major LDS) + attention logits ----------------
__global__ __launch_bounds__(256) void k_e1(
    const float* __restrict__ h, const float* __restrict__ x, const int* __restrict__ ei,
    const float* __restrict__ stats,
    const unsigned short* __restrict__ qb, const unsigned short* __restrict__ kb,
    const unsigned short* __restrict__ wfrag,
    const float* __restrict__ eb1, const float* __restrict__ eb2,
    const float* __restrict__ eww, const float* __restrict__ ewb,
    const float* __restrict__ pw1, const float* __restrict__ pb1,
    const float* __restrict__ pw2, const float* __restrict__ pb2,
    float* __restrict__ asum, float* __restrict__ eattn){
  __shared__ __align__(16) unsigned short bufIn[64*24*8];  // K<=192 row-major swizzled
  __shared__ __align__(16) unsigned short bufA [64*16*8];  // K=128
  __shared__ float ewt_s[256], logit_s[256];
  __shared__ float rd_s[64], xnr_s[192], xnc_s[192];
  __shared__ int row_s[64], col_s[64];
  int t = threadIdx.x; int lane = t & 63; int w = t >> 6;
  int wu = __builtin_amdgcn_readfirstlane(w);
  int ebase = blockIdx.x * 64;

  if (t < 64){
    int ge = ebase + t;
    int r = ei[ge], c = ei[NE+ge];
    row_s[t]=r; col_s[t]=c;
    float xr0=x[r*3],xr1=x[r*3+1],xr2=x[r*3+2];
    float xc0=x[c*3],xc1=x[c*3+1],xc2=x[c*3+2];
    float rp0=xr0-xc0, rp1=xr1-xc1, rp2=xr2-xc2;
    rd_s[t]=rp0*rp0+rp1*rp1+rp2*rp2;
    float m0=stats[6],m1=stats[7],m2=stats[8],s0=stats[9],s1=stats[10],s2=stats[11];
    xnr_s[t*3+0]=(xr0-m0)*s0; xnr_s[t*3+1]=(xr1-m1)*s1; xnr_s[t*3+2]=(xr2-m2)*s2;
    xnc_s[t*3+0]=(xc0-m0)*s0; xnc_s[t*3+1]=(xc1-m1)*s1; xnc_s[t*3+2]=(xc2-m2)*s2;
    #pragma unroll
    for (int hh=0;hh<4;hh++) ewt_s[t*4+hh] = ewb[hh] + pb2[hh];
  }
  __syncthreads();

  // q.k dots
  for (int ii=0; ii<16; ii++){
    int e = wu*16+ii;
    int r = row_s[e], c = col_s[e];
    uint2 qu = *(const uint2*)(qb + (size_t)r*256 + lane*4);
    uint2 ku = *(const uint2*)(kb + (size_t)c*256 + lane*4);
    float d = bf2f(qu.x&0xffffu)*bf2f(ku.x&0xffffu)
            + bf2f(qu.x>>16)   *bf2f(ku.x>>16)
            + bf2f(qu.y&0xffffu)*bf2f(ku.y&0xffffu)
            + bf2f(qu.y>>16)   *bf2f(ku.y>>16);
    d += __shfl_xor(d,1,16); d += __shfl_xor(d,2,16);
    d += __shfl_xor(d,4,16); d += __shfl_xor(d,8,16);
    if ((lane&15)==0) logit_s[e*4 + (lane>>4)] = d*0.125f;
  }
  // pos_enc partials
  {
    int jb = wu*16;
    float rd = rd_s[lane];
    float p0=0,p1=0,p2=0,p3=0;
    for (int j=jb; j<jb+16; j++){
      float hp = rd*pw1[j] + pb1[j];
      float hs = silu_f(hp);
      const float4 w4 = *(const float4*)(pw2 + j*4);
      p0+=hs*w4.x; p1+=hs*w4.y; p2+=hs*w4.z; p3+=hs*w4.w;
    }
    atomicAdd(&ewt_s[lane*4+0],p0); atomicAdd(&ewt_s[lane*4+1],p1);
    atomicAdd(&ewt_s[lane*4+2],p2); atomicAdd(&ewt_s[lane*4+3],p3);
  }
  // stage row-major: k 0..63 h[row], 64..127 h[col], 128..134 extras, rest zero
  {
    const float* hr = h + (size_t)row_s[lane]*64 + wu*16;
    pack8(&bufIn[lidx(lane, 2*wu,   24)], *(const float4*)(hr),   *(const float4*)(hr+4));
    pack8(&bufIn[lidx(lane, 2*wu+1, 24)], *(const float4*)(hr+8), *(const float4*)(hr+12));
    const float* hc = h + (size_t)col_s[lane]*64 + wu*16;
    pack8(&bufIn[lidx(lane, 8+2*wu, 24)], *(const float4*)(hc),   *(const float4*)(hc+4));
    pack8(&bufIn[lidx(lane, 9+2*wu, 24)], *(const float4*)(hc+8), *(const float4*)(hc+12));
  }
  if (t < 64){
    pack8(&bufIn[lidx(t,16,24)],
          make_float4(rd_s[t], xnr_s[t*3+0], xnr_s[t*3+1], xnr_s[t*3+2]),
          make_float4(xnc_s[t*3+0], xnc_s[t*3+1], xnc_s[t*3+2], 0.f));
  }
  {
    uint4 z4 = make_uint4(0,0,0,0);
    int e = t&63, j = t>>6;
    *(uint4*)&bufIn[lidx(e, 17+j, 24)] = z4;
    if (j < 3) *(uint4*)&bufIn[lidx(e, 21+j, 24)] = z4;
  }
  __syncthreads();
  f4v acc[4][2];
  f4v z = {0.f,0.f,0.f,0.f};
  // G1: ew1 (KC=5) -> silu(+eb1) -> bufA
  #pragma unroll
  for (int et=0;et<4;et++){ acc[et][0]=z; acc[et][1]=z; }
  gemm_rm<5,24>(bufIn, wfrag + 0, wu, lane, acc);
  epi_rm<16,true,true>(bufA, acc, eb1, wu, lane);
  __syncthreads();
  // G2: ew2 (KC=4) -> ef(+eb2) -> bufIn chunks 0..15
  #pragma unroll
  for (int et=0;et<4;et++){ acc[et][0]=z; acc[et][1]=z; }
  gemm_rm<4,16>(bufA, wfrag + 20480, wu, lane, acc);
  epi_rm<24,false,true>(bufIn, acc, eb2, wu, lane);
  __syncthreads();
  // eww partials from ef (row-major read, lane = edge; wave wu -> cols wu*32..+31)
  {
    float p[4]; dot4<24>(bufIn, wu, lane, eww, p);
    atomicAdd(&ewt_s[lane*4+0],p[0]); atomicAdd(&ewt_s[lane*4+1],p[1]);
    atomicAdd(&ewt_s[lane*4+2],p[2]); atomicAdd(&ewt_s[lane*4+3],p[3]);
  }
  __syncthreads();
  {
    int e = t>>2;
    float lg = logit_s[t] + ewt_s[t];
    float ex = __expf(lg);
    eattn[(size_t)ebase*4 + t] = ex;
    atomicAdd(&asum[row_s[e]*4 + (t&3)], ex);
  }
}

// ---------------- E2: recompute ef + message MLP + heads (MFMA, row-major LDS) ----------------
__global__ __launch_bounds__(256) void k_e2(
    const float* __restrict__ h, const float* __restrict__ x, const int* __restrict__ ei,
    const float* __restrict__ stats,
    const float* __restrict__ asum, float* __restrict__ eattn,
    const unsigned short* __restrict__ wfrag,
    const float* __restrict__ eb1, const float* __restrict__ eb2,
    const float* __restrict__ mb1, const float* __restrict__ mb2,
    const float* __restrict__ gw, const float* __restrict__ gb,
    const float* __restrict__ cb1, const float* __restrict__ cw2, const float* __restrict__ cb2,
    const float* __restrict__ coordw,
    const float* __restrict__ xb1, const float* __restrict__ xw2, const float* __restrict__ xb2,
    float* __restrict__ cvec){
  __shared__ __align__(16) unsigned short bufIn[64*24*8];
  __shared__ __align__(16) unsigned short bufA [64*16*8];
  __shared__ float attn_s[256];
  __shared__ float g_s[256], c_s[256], xx_s[256];
  __shared__ float s_s[64], cs_s[64];
  __shared__ float rp_s[192], rd_s[64], xnr_s[192], xnc_s[192], xc_s[192];
  __shared__ int row_s[64], col_s[64];
  int t = threadIdx.x; int lane = t & 63; int w = t >> 6;
  int wu = __builtin_amdgcn_readfirstlane(w);
  int ebase = blockIdx.x * 64;

  if (t < 64){
    int ge = ebase + t;
    int r = ei[ge], c = ei[NE+ge];
    row_s[t]=r; col_s[t]=c;
    float xr0=x[r*3],xr1=x[r*3+1],xr2=x[r*3+2];
    float xc0=x[c*3],xc1=x[c*3+1],xc2=x[c*3+2];
    float rp0=xr0-xc0, rp1=xr1-xc1, rp2=xr2-xc2;
    rp_s[t*3+0]=rp0; rp_s[t*3+1]=rp1; rp_s[t*3+2]=rp2;
    rd_s[t]=rp0*rp0+rp1*rp1+rp2*rp2;
    xc_s[t*3+0]=xc0; xc_s[t*3+1]=xc1; xc_s[t*3+2]=xc2;
    float m0=stats[6],m1=stats[7],m2=stats[8],s0=stats[9],s1=stats[10],s2=stats[11];
    xnr_s[t*3+0]=(xr0-m0)*s0; xnr_s[t*3+1]=(xr1-m1)*s1; xnr_s[t*3+2]=(xr2-m2)*s2;
    xnc_s[t*3+0]=(xc0-m0)*s0; xnc_s[t*3+1]=(xc1-m1)*s1; xnc_s[t*3+2]=(xc2-m2)*s2;
    s_s[t]=0.f; cs_s[t]=0.f;
  }
  g_s[t]=0.f; c_s[t]=0.f; xx_s[t]=0.f;
  __syncthreads();
  // attn normalize (write back for k_aggout)
  {
    int e = t>>2; int hh = t&3;
    float ex = eattn[(size_t)ebase*4 + t];
    float a = ex / (asum[row_s[e]*4 + hh] + 1e-8f);
    attn_s[t]=a;
    eattn[(size_t)ebase*4 + t]=a;
  }
  // stage row-major input (same as k_e1)
  {
    const float* hr = h + (size_t)row_s[lane]*64 + wu*16;
    pack8(&bufIn[lidx(lane, 2*wu,   24)], *(const float4*)(hr),   *(const float4*)(hr+4));
    pack8(&bufIn[lidx(lane, 2*wu+1, 24)], *(const float4*)(hr+8), *(const float4*)(hr+12));
    const float* hc = h + (size_t)col_s[lane]*64 + wu*16;
    pack8(&bufIn[lidx(lane, 8+2*wu, 24)], *(const float4*)(hc),   *(const float4*)(hc+4));
    pack8(&bufIn[lidx(lane, 9+2*wu, 24)], *(const float4*)(hc+8), *(const float4*)(hc+12));
  }
  if (t < 64){
    pack8(&bufIn[lidx(t,16,24)],
          make_float4(rd_s[t], xnr_s[t*3+0], xnr_s[t*3+1], xnr_s[t*3+2]),
          make_float4(xnc_s[t*3+0], xnc_s[t*3+1], xnc_s[t*3+2], 0.f));
  }
  {
    uint4 z4 = make_uint4(0,0,0,0);
    int e = t&63, j = t>>6;
    *(uint4*)&bufIn[lidx(e, 17+j, 24)] = z4;
    if (j < 3) *(uint4*)&bufIn[lidx(e, 21+j, 24)] = z4;
  }
  __syncthreads();
  f4v acc[4][2];
  f4v z = {0.f,0.f,0.f,0.f};
  // G1: ew1 -> silu -> bufA
  #pragma unroll
  for (int et=0;et<4;et++){ acc[et][0]=z; acc[et][1]=z; }
  gemm_rm<5,24>(bufIn, wfrag + 0, wu, lane, acc);
  epi_rm<16,true,true>(bufA, acc, eb1, wu, lane);
  __syncthreads();
  // G2: ew2 -> ef -> bufIn chunks 0..15; rewrite extras (chunks 16,17) for mw1
  #pragma unroll
  for (int et=0;et<4;et++){ acc[et][0]=z; acc[et][1]=z; }
  gemm_rm<4,16>(bufA, wfrag + 20480, wu, lane, acc);
  epi_rm<24,false,true>(bufIn, acc, eb2, wu, lane);
  if (t < 64){
    float am = 0.25f*(attn_s[t*4]+attn_s[t*4+1]+attn_s[t*4+2]+attn_s[t*4+3]);
    pack8(&bufIn[lidx(t,16,24)],
          make_float4(am, rp_s[t*3+0], rp_s[t*3+1], rp_s[t*3+2]),
          make_float4(xnr_s[t*3+0], xnr_s[t*3+1], xnr_s[t*3+2], xnc_s[t*3+0]));
    pack8(&bufIn[lidx(t,17,24)],
          make_float4(xnc_s[t*3+1], xnc_s[t*3+2], 0.f, 0.f),
          make_float4(0.f,0.f,0.f,0.f));
  }
  __syncthreads();
  // G3: mw1 (KC=5) -> silu -> bufA
  #pragma unroll
  for (int et=0;et<4;et++){ acc[et][0]=z; acc[et][1]=z; }
  gemm_rm<5,24>(bufIn, wfrag + 36864, wu, lane, acc);
  epi_rm<16,true,true>(bufA, acc, mb1, wu, lane);
  __syncthreads();
  // G4: mw2 -> msgs(+mb2) -> bufIn chunks 0..15
  #pragma unroll
  for (int et=0;et<4;et++){ acc[et][0]=z; acc[et][1]=z; }
  gemm_rm<4,16>(bufA, wfrag + 57344, wu, lane, acc);
  epi_rm<24,false,true>(bufIn, acc, mb2, wu, lane);
  __syncthreads();
  // gates partials from msgs (wave wu -> cols wu*32..+31)
  {
    float p[4]; dot4<24>(bufIn, wu, lane, gw, p);
    atomicAdd(&g_s[lane*4+0],p[0]); atomicAdd(&g_s[lane*4+1],p[1]);
    atomicAdd(&g_s[lane*4+2],p[2]); atomicAdd(&g_s[lane*4+3],p[3]);
  }
  // G5+G6: cw1 & xw1 from msgs (share B loads)
  f4v ax[4][2];
  #pragma unroll
  for (int et=0;et<4;et++){ acc[et][0]=z; acc[et][1]=z; ax[et][0]=z; ax[et][1]=z; }
  {
    const unsigned short* wfc = wfrag + 73728;
    const unsigned short* wfx = wfrag + 90112;
    int le = lane&15, quad = lane>>4;
    #pragma unroll
    for (int kc=0;kc<4;kc++){
      bf16x8 ac0 = *(const bf16x8*)(wfc + (((wu*2  )*4 + kc)<<9) + lane*8);
      bf16x8 ac1 = *(const bf16x8*)(wfc + (((wu*2+1)*4 + kc)<<9) + lane*8);
      bf16x8 ax0 = *(const bf16x8*)(wfx + (((wu*2  )*4 + kc)<<9) + lane*8);
      bf16x8 ax1 = *(const bf16x8*)(wfx + (((wu*2+1)*4 + kc)<<9) + lane*8);
      int chunk = kc*4 + quad;
      #pragma unroll
      for (int et=0;et<4;et++){
        bf16x8 b = *(const bf16x8*)(bufIn + lidx(et*16+le, chunk, 24));
        acc[et][0] = __builtin_amdgcn_mfma_f32_16x16x32_bf16(ac0, b, acc[et][0], 0,0,0);
        acc[et][1] = __builtin_amdgcn_mfma_f32_16x16x32_bf16(ac1, b, acc[et][1], 0,0,0);
        ax[et][0]  = __builtin_amdgcn_mfma_f32_16x16x32_bf16(ax0, b, ax[et][0], 0,0,0);
        ax[et][1]  = __builtin_amdgcn_mfma_f32_16x16x32_bf16(ax1, b, ax[et][1], 0,0,0);
      }
    }
  }
  __syncthreads();   // all waves done reading bufA (G4) & bufIn (G5/6 + gw)
  epi_rm<16,true,true>(bufA, acc, cb1, wu, lane);   // silu(cpre+cb1)
  __syncthreads();
  {
    float p[4]; dot4<16>(bufA, wu, lane, cw2, p);
    atomicAdd(&c_s[lane*4+0],p[0]); atomicAdd(&c_s[lane*4+1],p[1]);
    atomicAdd(&c_s[lane*4+2],p[2]); atomicAdd(&c_s[lane*4+3],p[3]);
  }
  __syncthreads();
  epi_rm<16,true,true>(bufA, ax, xb1, wu, lane);    // silu(xpre+xb1)
  __syncthreads();
  {
    float p[4]; dot4<16>(bufA, wu, lane, xw2, p);
    atomicAdd(&xx_s[lane*4+0],p[0]); atomicAdd(&xx_s[lane*4+1],p[1]);
    atomicAdd(&xx_s[lane*4+2],p[2]); atomicAdd(&xx_s[lane*4+3],p[3]);
  }
  __syncthreads();
  // combine heads
  {
    int e = t>>2; int hh = t&3;
    float g = 1.0f/(1.0f+__expf(-(g_s[t]+gb[hh])));
    float cwv = c_s[t]+cb2[hh];
    atomicAdd(&s_s[e], g*cwv*coordw[hh]);
    atomicAdd(&cs_s[e], xx_s[t]+xb2[hh]);
  }
  __syncthreads();
  if (t < 64){
    int ge = ebase + t;
    float rp0=rp_s[t*3],rp1=rp_s[t*3+1],rp2=rp_s[t*3+2];
    float pp0,pp1,pp2;
    if (t > 0){ pp0=rp_s[(t-1)*3]; pp1=rp_s[(t-1)*3+1]; pp2=rp_s[(t-1)*3+2]; }
    else {
      int gp = (ebase==0)? (NE-1) : (ebase-1);
      int rr=ei[gp], cc2=ei[NE+gp];
      pp0=x[rr*3]-x[cc2*3]; pp1=x[rr*3+1]-x[cc2*3+1]; pp2=x[rr*3+2]-x[cc2*3+2];
    }
    float cv0 = rp1*pp2 - rp2*pp1;
    float cv1 = rp2*pp0 - rp0*pp2;
    float cv2 = rp0*pp1 - rp1*pp0;
    float sv = s_s[t], csv = cs_s[t];
    const float inv = 1.0f/49999.0f;
    cvec[(size_t)ge*3+0] = (sv*(0.9f*rp0+0.1f*xc_s[t*3+0]) + csv*cv0)*inv;
    cvec[(size_t)ge*3+1] = (sv*(0.9f*rp1+0.1f*xc_s[t*3+1]) + csv*cv1)*inv;
    cvec[(size_t)ge*3+2] = (sv*(0.9f*rp2+0.1f*xc_s[t*3+2]) + csv*cv2)*inv;
  }
}

// ---------------- fused aggregation + out GEMM: one wave per node ----------------
__global__ __launch_bounds__(256) void k_aggout(
    const int* __restrict__ ei, const int* __restrict__ offs, const int* __restrict__ elist,
    const float* __restrict__ eattn, const unsigned short* __restrict__ vb,
    const float* __restrict__ cvec, const float* __restrict__ Wo, const float* __restrict__ bo,
    float* __restrict__ outp){
  __shared__ float wvs[4*256];
  int t = threadIdx.x; int lane = t & 63; int w = t >> 6;
  int node = blockIdx.x*4 + w;
  const int* colp = ei + NE;
  int s0 = offs[node], s1 = offs[node+1];
  float a0=0,a1=0,a2=0,a3=0,cc=0;
  int i = s0;
  for (; i+4<=s1; i+=4){
    int e0=elist[i], e1=elist[i+1], e2=elist[i+2], e3=elist[i+3];
    int c0=colp[e0], c1=colp[e1], c2=colp[e2], c3=colp[e3];
    uint2 v0 = *(const uint2*)(vb + (size_t)c0*256 + lane*4);
    uint2 v1 = *(const uint2*)(vb + (size_t)c1*256 + lane*4);
    uint2 v2 = *(const uint2*)(vb + (size_t)c2*256 + lane*4);
    uint2 v3 = *(const uint2*)(vb + (size_t)c3*256 + lane*4);
    float4 at0 = *(const float4*)(eattn + (size_t)e0*4);
    float4 at1 = *(const float4*)(eattn + (size_t)e1*4);
    float4 at2 = *(const float4*)(eattn + (size_t)e2*4);
    float4 at3 = *(const float4*)(eattn + (size_t)e3*4);
    if (lane < 3) cc += cvec[(size_t)e0*3+lane] + cvec[(size_t)e1*3+lane]
                      + cvec[(size_t)e2*3+lane] + cvec[(size_t)e3*3+lane];
    a0 += at0.x*bf2f(v0.x&0xffffu) + at1.x*bf2f(v1.x&0xffffu) + at2.x*bf2f(v2.x&0xffffu) + at3.x*bf2f(v3.x&0xffffu);
    a1 += at0.y*bf2f(v0.x>>16)     + at1.y*bf2f(v1.x>>16)     + at2.y*bf2f(v2.x>>16)     + at3.y*bf2f(v3.x>>16);
    a2 += at0.z*bf2f(v0.y&0xffffu) + at1.z*bf2f(v1.y&0xffffu) + at2.z*bf2f(v2.y&0xffffu) + at3.z*bf2f(v3.y&0xffffu);
    a3 += at0.w*bf2f(v0.y>>16)     + at1.w*bf2f(v1.y>>16)     + at2.w*bf2f(v2.y>>16)     + at3.w*bf2f(v3.y>>16);
  }
  for (; i<s1; i++){
    int e0 = elist[i];
    int c0 = colp[e0];
    uint2 v0 = *(const uint2*)(vb + (size_t)c0*256 + lane*4);
    float4 at0 = *(const float4*)(eattn + (size_t)e0*4);
    if (lane < 3) cc += cvec[(size_t)e0*3+lane];
    a0 += at0.x*bf2f(v0.x&0xffffu);
    a1 += at0.y*bf2f(v0.x>>16);
    a2 += at0.z*bf2f(v0.y&0xffffu);
    a3 += at0.w*bf2f(v0.y>>16);
  }
  wvs[w*256 +       lane]=a0;
  wvs[w*256 +  64 + lane]=a1;
  wvs[w*256 + 128 + lane]=a2;
  wvs[w*256 + 192 + lane]=a3;
  if (lane < 3) outp[(size_t)NN*64 + (size_t)node*3 + lane] = cc;
  float o = bo[lane];
  #pragma unroll 4
  for (int k2=0;k2<256;k2++) o += wvs[w*256+k2] * Wo[k2*64+lane];
  outp[(size_t)node*64 + lane] = o;
}

extern "C" void kernel_launch(void* const* d_in, const int* in_sizes, int n_in,
                              void* d_out, int out_size, void* d_ws, size_t ws_size,
                              hipStream_t stream) {
  const float* h  = (const float*)d_in[0];
  const float* x  = (const float*)d_in[1];
  const int*   ei = (const int*)d_in[2];
  // d_in[3] = mask (all true)
  const float* Wq=(const float*)d_in[4];  const float* bq=(const float*)d_in[5];
  const float* Wk=(const float*)d_in[6];  const float* bk=(const float*)d_in[7];
  const float* Wv=(const float*)d_in[8];  const float* bv=(const float*)d_in[9];
  const float* Wo=(const float*)d_in[10]; const float* bo=(const float*)d_in[11];
  const float* pw1=(const float*)d_in[12]; const float* pb1=(const float*)d_in[13];
  const float* pw2=(const float*)d_in[14]; const float* pb2=(const float*)d_in[15];
  const float* ew1=(const float*)d_in[16]; const float* eb1=(const float*)d_in[17];
  const float* ew2=(const float*)d_in[18]; const float* eb2=(const float*)d_in[19];
  const float* eww=(const float*)d_in[20]; const float* ewb=(const float*)d_in[21];
  const float* mw1=(const float*)d_in[22]; const float* mb1=(const float*)d_in[23];
  const float* mw2=(const float*)d_in[24]; const float* mb2=(const float*)d_in[25];
  const float* gw=(const float*)d_in[26];  const float* gb=(const float*)d_in[27];
  const float* cw1=(const float*)d_in[28]; const float* cb1=(const float*)d_in[29];
  const float* cw2=(const float*)d_in[30]; const float* cb2=(const float*)d_in[31];
  const float* coordw=(const float*)d_in[32];
  const float* xw1=(const float*)d_in[33]; const float* xb1=(const float*)d_in[34];
  const float* xw2=(const float*)d_in[35]; const float* xb2=(const float*)d_in[36];

  // workspace layout (bytes), high-water = 103,813,088
  char* B = (char*)d_ws;
  float* eattn = (float*)(B + 0);                        // E*4*4   = 12,800,000
  float* cvec  = (float*)(B + 12800000);                 // E*3*4   =  9,600,000
  float* stats = (float*)(B + 22400000);                 // 64
  float* asum  = (float*)(B + 22400064);                 // N*4*4   =    800,000
  int* counts  = (int*)(B + 23200064);                   // N*4     =    200,000  (also cursor)
  int* offs    = (int*)(B + 23400064);                   // (N+1)*4 =    200,004
  unsigned short* wfrag = (unsigned short*)(B + 23600080); // 106,496 bf16 = 212,992
  int* elist   = (int*)(B + 23813088);                   // E*4     =  3,200,000
  unsigned short* qb = (unsigned short*)(B + 27013088);  // N*256*2 = 25,600,000
  unsigned short* kb = (unsigned short*)(B + 52613088);  // N*256*2 = 25,600,000
  unsigned short* vb = (unsigned short*)(B + 78213088);  // N*256*2 = 25,600,000

  // zero stats+asum+counts (contiguous 1,000,064 B)
  k_zero<<<977,256,0,stream>>>(stats, 250016);
  // weight fragment prep (bf16, MFMA A-frag layout; identical packing to B-frag)
  k_wprep<<<80,256,0,stream>>>(ew1, wfrag + 0,     135, 5);
  k_wprep<<<64,256,0,stream>>>(ew2, wfrag + 20480, 128, 4);
  k_wprep<<<80,256,0,stream>>>(mw1, wfrag + 36864, 138, 5);
  k_wprep<<<64,256,0,stream>>>(mw2, wfrag + 57344, 128, 4);
  k_wprep<<<64,256,0,stream>>>(cw1, wfrag + 73728, 128, 4);
  k_wprep<<<64,256,0,stream>>>(xw1, wfrag + 90112, 128, 4);

  k_stats<<<196,256,0,stream>>>(x, stats);
  k_statsfin<<<1,64,0,stream>>>(stats);
  k_qkv<<<dim3(1563,12),256,0,stream>>>(h,Wq,bq,Wk,bk,Wv,bv,qb,kb,vb);
  k_count<<<3125,256,0,stream>>>(ei,counts);
  k_scan<<<1,256,0,stream>>>(counts,offs);
  k_fill<<<3125,256,0,stream>>>(ei,counts,elist);
  k_e1<<<12500,256,0,stream>>>(h,x,ei,stats,qb,kb,wfrag,eb1,eb2,eww,ewb,pw1,pb1,pw2,pb2,asum,eattn);
  k_e2<<<12500,256,0,stream>>>(h,x,ei,stats,asum,eattn,wfrag,eb1,eb2,mb1,mb2,gw,gb,cb1,cw2,cb2,coordw,xb1,xw2,xb2,cvec);
  k_aggout<<<12500,256,0,stream>>>(ei,offs,elist,eattn,vb,cvec,Wo,bo,(float*)d_out);
}

// Round 8
// 1816.828 us; speedup vs baseline: 1.1160x; 1.1160x over previous
//
#include <hip/hip_runtime.h>
#include <hip/hip_bf16.h>

#define NN 50000
#define NE 800000

typedef __bf16 bf16x8 __attribute__((ext_vector_type(8)));
typedef float f4v __attribute__((ext_vector_type(4)));

__device__ __forceinline__ float silu_f(float v){ return v/(1.0f+__expf(-v)); }
__device__ __forceinline__ float bf2f(unsigned int u){ return __uint_as_float(u<<16); }
__device__ __forceinline__ unsigned short f2bf(float f){ __hip_bfloat16 b=__float2bfloat16(f); return *reinterpret_cast<unsigned short*>(&b); }
__device__ __forceinline__ unsigned pk2(float a, float b){ return (unsigned)f2bf(a) | ((unsigned)f2bf(b)<<16); }

union U8 { unsigned short us[8]; uint4 u4; };

__device__ __forceinline__ void pack8(unsigned short* dst, float4 a, float4 b){
  uint4 u;
  u.x = pk2(a.x,a.y); u.y = pk2(a.z,a.w);
  u.z = pk2(b.x,b.y); u.w = pk2(b.z,b.w);
  *(uint4*)dst = u;
}
__device__ __forceinline__ void unpack8(uint4 u, float* f){
  f[0]=bf2f(u.x&0xffffu); f[1]=bf2f(u.x>>16);
  f[2]=bf2f(u.y&0xffffu); f[3]=bf2f(u.y>>16);
  f[4]=bf2f(u.z&0xffffu); f[5]=bf2f(u.z>>16);
  f[6]=bf2f(u.w&0xffffu); f[7]=bf2f(u.w>>16);
}

// short-index of 16B chunk c of row e in a row-major swizzled activation buffer
// (CH = chunks per row, multiple of 8; chunk swizzled within its group of 8)
__device__ __forceinline__ int lidx(int e, int c, int CH){
  return (e*CH + ((c & ~7) | ((c ^ e) & 7))) << 3;
}

// GEMM: A = weights (global frag order), B = activations (row-major swizzled LDS).
// acc[et][ot]: D rows = outcols (wu*32+ot*16+quad*4+r), cols = edges (et*16+(lane&15)).
template<int KC, int CH>
__device__ __forceinline__ void gemm_rm(const unsigned short* act, const unsigned short* wf,
                                        int wu, int lane, f4v (&acc)[4][2]){
  int le = lane & 15, quad = lane >> 4;
  #pragma unroll
  for (int kc=0;kc<KC;kc++){
    bf16x8 a0 = *(const bf16x8*)(wf + (((wu*2  )*KC + kc)<<9) + lane*8);
    bf16x8 a1 = *(const bf16x8*)(wf + (((wu*2+1)*KC + kc)<<9) + lane*8);
    int chunk = kc*4 + quad;
    #pragma unroll
    for (int et=0;et<4;et++){
      bf16x8 b = *(const bf16x8*)(act + lidx(et*16+le, chunk, CH));
      acc[et][0] = __builtin_amdgcn_mfma_f32_16x16x32_bf16(a0, b, acc[et][0], 0,0,0);
      acc[et][1] = __builtin_amdgcn_mfma_f32_16x16x32_bf16(a1, b, acc[et][1], 0,0,0);
    }
  }
}

// epilogue: D regs -> row-major swizzled bf16 buffer, packed b64 stores
template<int CH, bool SILU, bool BIAS>
__device__ __forceinline__ void epi_rm(unsigned short* dst, const f4v (&acc)[4][2],
                                       const float* bias, int wu, int lane){
  int le = lane & 15, quad = lane >> 4;
  #pragma unroll
  for (int ot=0; ot<2; ot++){
    float4 bv = make_float4(0,0,0,0);
    if (BIAS) bv = *(const float4*)(bias + wu*32 + ot*16 + quad*4);
    int chunk = wu*4 + ot*2 + (quad>>1);
    int soff = (quad&1)*4;
    #pragma unroll
    for (int et=0; et<4; et++){
      float v0=acc[et][ot][0], v1=acc[et][ot][1], v2=acc[et][ot][2], v3=acc[et][ot][3];
      if (BIAS){ v0+=bv.x; v1+=bv.y; v2+=bv.z; v3+=bv.w; }
      if (SILU){ v0=silu_f(v0); v1=silu_f(v1); v2=silu_f(v2); v3=silu_f(v3); }
      uint2 u; u.x = pk2(v0,v1); u.y = pk2(v2,v3);
      *(uint2*)(dst + lidx(et*16+le, chunk, CH) + soff) = u;
    }
  }
}

// per-edge (lane = edge) FULL 128-dot for ONE head (wu): plain store, no atomics.
// W is [128][4] row-major; weight loads are wave-uniform -> s_load.
template<int CH>
__device__ __forceinline__ float dot128(const unsigned short* buf, int wu, int lane,
                                        const float* __restrict__ W){
  float p = 0.f;
  #pragma unroll
  for (int c=0;c<16;c++){
    uint4 u = *(const uint4*)(buf + lidx(lane, c, CH));
    float f[8]; unpack8(u,f);
    #pragma unroll
    for (int j=0;j<8;j++) p += f[j]*W[(c*8+j)*4 + wu];
  }
  return p;
}

// ---------------- zero a span ----------------
__global__ __launch_bounds__(256) void k_zero(float* __restrict__ p, int n){
  int i = blockIdx.x*256 + threadIdx.x;
  if (i < n) p[i] = 0.f;
}

// ---------------- weight pre-pack into MFMA fragment order (bf16) ----------------
__global__ __launch_bounds__(256) void k_wprep(const float* __restrict__ src, unsigned short* __restrict__ dst,
                                               int Kreal, int KC){
  int idx = blockIdx.x*256 + threadIdx.x;
  int tot = 8*KC*512;
  if (idx >= tot) return;
  int nt  = idx/(KC*512); int rem = idx%(KC*512);
  int kc  = rem>>9;       int r2  = rem&511;
  int lq  = r2>>3;        int j   = r2&7;
  int k   = kc*32 + (lq>>4)*8 + j;
  int n   = nt*16 + (lq&15);
  float v = (k < Kreal) ? src[k*128 + n] : 0.f;
  dst[idx] = f2bf(v);
}

// ---------------- stats ----------------
__global__ __launch_bounds__(256) void k_stats(const float* __restrict__ x, float* __restrict__ stats){
  int i = blockIdx.x*256 + threadIdx.x;
  float v0=0.f,v1=0.f,v2=0.f;
  if (i < NN){ v0=x[i*3+0]; v1=x[i*3+1]; v2=x[i*3+2]; }
  float vals[6] = {v0,v1,v2,v0*v0,v1*v1,v2*v2};
  __shared__ float red[256];
  for (int c=0;c<6;c++){
    red[threadIdx.x]=vals[c];
    __syncthreads();
    for (int off=128; off>0; off>>=1){
      if (threadIdx.x < off) red[threadIdx.x] += red[threadIdx.x+off];
      __syncthreads();
    }
    if (threadIdx.x==0) atomicAdd(&stats[c], red[0]);
    __syncthreads();
  }
}

__global__ __launch_bounds__(64) void k_statsfin(float* __restrict__ stats){
  int t = threadIdx.x;
  if (t < 3){
    float s = stats[t], sq = stats[3+t];
    float mean = s/(float)NN;
    float var = (sq - s*s/(float)NN)/(float)(NN-1);
    float sd = sqrtf(var);
    stats[6+t] = mean;
    stats[9+t] = 1.0f/(sd + 1e-8f);
  }
}

// ---------------- q,k,v = h @ W + b  (bf16 out; v stored [node][d][head]) ----------------
__global__ __launch_bounds__(256) void k_qkv(const float* __restrict__ h,
    const float* __restrict__ Wq, const float* __restrict__ bq,
    const float* __restrict__ Wk, const float* __restrict__ bk,
    const float* __restrict__ Wv, const float* __restrict__ bv,
    unsigned short* __restrict__ q, unsigned short* __restrict__ kk, unsigned short* __restrict__ v){
  __shared__ float hs[32*68];
  int t = threadIdx.x;
  int by = blockIdx.y;
  int mat = by>>2; int quarter = by&3; int colbase = quarter*64;
  const float* W; const float* bb; unsigned short* outp;
  if (mat==0){W=Wq;bb=bq;outp=q;} else if (mat==1){W=Wk;bb=bk;outp=kk;} else {W=Wv;bb=bv;outp=v;}
  int r0 = blockIdx.x*32;
  {
    int rw = t>>3; int c0 = (t&7)*8;
    int row = r0 + rw;
    float4 a = make_float4(0,0,0,0), b2 = make_float4(0,0,0,0);
    if (row < NN){
      a  = *(const float4*)(h + (size_t)row*64 + c0);
      b2 = *(const float4*)(h + (size_t)row*64 + c0 + 4);
    }
    *(float4*)(&hs[rw*68 + c0])     = a;
    *(float4*)(&hs[rw*68 + c0 + 4]) = b2;
  }
  __syncthreads();
  int rg = t>>3; int cg = t&7; int col = colbase + cg*8;
  float acc[8];
  #pragma unroll
  for (int j=0;j<8;j++) acc[j]=0.f;
  for (int k2=0;k2<64;k2++){
    float a = hs[rg*68 + k2];
    const float4 w0 = *(const float4*)(W + k2*256 + col);
    const float4 w1 = *(const float4*)(W + k2*256 + col + 4);
    acc[0]+=a*w0.x; acc[1]+=a*w0.y; acc[2]+=a*w0.z; acc[3]+=a*w0.w;
    acc[4]+=a*w1.x; acc[5]+=a*w1.y; acc[6]+=a*w1.z; acc[7]+=a*w1.w;
  }
  int row = r0 + rg;
  if (row < NN){
    if (mat==2){
      #pragma unroll
      for (int j=0;j<8;j++) outp[(size_t)row*256 + (size_t)(cg*8+j)*4 + quarter] = f2bf(acc[j]+bb[col+j]);
    } else {
      U8 u;
      #pragma unroll
      for (int j=0;j<8;j++) u.us[j] = f2bf(acc[j]+bb[col+j]);
      *(uint4*)(outp + (size_t)row*256 + col) = u.u4;
    }
  }
}

// ---------------- CSR build ----------------
__global__ __launch_bounds__(256) void k_count(const int* __restrict__ ei, int* __restrict__ counts){
  int e = blockIdx.x*256 + threadIdx.x;
  if (e < NE) atomicAdd(&counts[ei[e]], 1);
}

__global__ __launch_bounds__(256) void k_scan(int* __restrict__ counts, int* __restrict__ offs){
  __shared__ int ps[256];
  int t = threadIdx.x;
  int base = t*196;
  int s = 0;
  for (int i=0;i<196;i++){ int idx = base+i; if (idx < NN) s += counts[idx]; }
  ps[t]=s; __syncthreads();
  for (int off=1; off<256; off<<=1){
    int vv = (t>=off)? ps[t-off] : 0;
    __syncthreads();
    ps[t]+=vv;
    __syncthreads();
  }
  int run = ps[t]-s;
  for (int i=0;i<196;i++){
    int idx = base+i;
    if (idx < NN){ int c = counts[idx]; offs[idx]=run; counts[idx]=run; run+=c; }
  }
  if (t==255) offs[NN]=run;
}

__global__ __launch_bounds__(256) void k_fill(const int* __restrict__ ei, int* __restrict__ cursor, int* __restrict__ elist){
  int e = blockIdx.x*256 + threadIdx.x;
  if (e < NE){
    int r = ei[e];
    int p = atomicAdd(&cursor[r],1);
    elist[p] = e;
  }
}

// ---------------- E1: edge MLP (MFMA, row-major LDS) + attention logits ----------------
__global__ __launch_bounds__(256) void k_e1(
    const float* __restrict__ h, const float* __restrict__ x, const int* __restrict__ ei,
    const float* __restrict__ stats,
    const unsigned short* __restrict__ qb, const unsigned short* __restrict__ kb,
    const unsigned short* __restrict__ wfrag,
    const float* __restrict__ eb1, const float* __restrict__ eb2,
    const float* __restrict__ eww, const float* __restrict__ ewb,
    const float* __restrict__ pw1, const float* __restrict__ pb1,
    const float* __restrict__ pw2, const float* __restrict__ pb2,
    float* __restrict__ asum, float* __restrict__ eattn){
  __shared__ __align__(16) unsigned short bufIn[64*24*8];  // K<=192 row-major swizzled
  __shared__ __align__(16) unsigned short bufA [64*16*8];  // K=128
  __shared__ float ewt_s[256], logit_s[256];
  __shared__ float ewt2_s[4*65];   // [h][e]: eww dots, plain stores (wave h owns row h)
  __shared__ float rd_s[64], xnr_s[192], xnc_s[192];
  __shared__ int row_s[64], col_s[64];
  int t = threadIdx.x; int lane = t & 63; int w = t >> 6;
  int wu = __builtin_amdgcn_readfirstlane(w);
  int ebase = blockIdx.x * 64;

  if (t < 64){
    int ge = ebase + t;
    int r = ei[ge], c = ei[NE+ge];
    row_s[t]=r; col_s[t]=c;
    float xr0=x[r*3],xr1=x[r*3+1],xr2=x[r*3+2];
    float xc0=x[c*3],xc1=x[c*3+1],xc2=x[c*3+2];
    float rp0=xr0-xc0, rp1=xr1-xc1, rp2=xr2-xc2;
    rd_s[t]=rp0*rp0+rp1*rp1+rp2*rp2;
    float m0=stats[6],m1=stats[7],m2=stats[8],s0=stats[9],s1=stats[10],s2=stats[11];
    xnr_s[t*3+0]=(xr0-m0)*s0; xnr_s[t*3+1]=(xr1-m1)*s1; xnr_s[t*3+2]=(xr2-m2)*s2;
    xnc_s[t*3+0]=(xc0-m0)*s0; xnc_s[t*3+1]=(xc1-m1)*s1; xnc_s[t*3+2]=(xc2-m2)*s2;
    #pragma unroll
    for (int hh=0;hh<4;hh++) ewt_s[t*4+hh] = ewb[hh] + pb2[hh];
  }
  __syncthreads();

  // q.k dots
  for (int ii=0; ii<16; ii++){
    int e = wu*16+ii;
    int r = row_s[e], c = col_s[e];
    uint2 qu = *(const uint2*)(qb + (size_t)r*256 + lane*4);
    uint2 ku = *(const uint2*)(kb + (size_t)c*256 + lane*4);
    float d = bf2f(qu.x&0xffffu)*bf2f(ku.x&0xffffu)
            + bf2f(qu.x>>16)   *bf2f(ku.x>>16)
            + bf2f(qu.y&0xffffu)*bf2f(ku.y&0xffffu)
            + bf2f(qu.y>>16)   *bf2f(ku.y>>16);
    d += __shfl_xor(d,1,16); d += __shfl_xor(d,2,16);
    d += __shfl_xor(d,4,16); d += __shfl_xor(d,8,16);
    if ((lane&15)==0) logit_s[e*4 + (lane>>4)] = d*0.125f;
  }
  // pos_enc partials
  {
    int jb = wu*16;
    float rd = rd_s[lane];
    float p0=0,p1=0,p2=0,p3=0;
    for (int j=jb; j<jb+16; j++){
      float hp = rd*pw1[j] + pb1[j];
      float hs = silu_f(hp);
      const float4 w4 = *(const float4*)(pw2 + j*4);
      p0+=hs*w4.x; p1+=hs*w4.y; p2+=hs*w4.z; p3+=hs*w4.w;
    }
    atomicAdd(&ewt_s[lane*4+0],p0); atomicAdd(&ewt_s[lane*4+1],p1);
    atomicAdd(&ewt_s[lane*4+2],p2); atomicAdd(&ewt_s[lane*4+3],p3);
  }
  // stage row-major: k 0..63 h[row], 64..127 h[col], 128..134 extras, rest zero
  {
    const float* hr = h + (size_t)row_s[lane]*64 + wu*16;
    pack8(&bufIn[lidx(lane, 2*wu,   24)], *(const float4*)(hr),   *(const float4*)(hr+4));
    pack8(&bufIn[lidx(lane, 2*wu+1, 24)], *(const float4*)(hr+8), *(const float4*)(hr+12));
    const float* hc = h + (size_t)col_s[lane]*64 + wu*16;
    pack8(&bufIn[lidx(lane, 8+2*wu, 24)], *(const float4*)(hc),   *(const float4*)(hc+4));
    pack8(&bufIn[lidx(lane, 9+2*wu, 24)], *(const float4*)(hc+8), *(const float4*)(hc+12));
  }
  if (t < 64){
    pack8(&bufIn[lidx(t,16,24)],
          make_float4(rd_s[t], xnr_s[t*3+0], xnr_s[t*3+1], xnr_s[t*3+2]),
          make_float4(xnc_s[t*3+0], xnc_s[t*3+1], xnc_s[t*3+2], 0.f));
  }
  {
    uint4 z4 = make_uint4(0,0,0,0);
    int e = t&63, j = t>>6;
    *(uint4*)&bufIn[lidx(e, 17+j, 24)] = z4;
    if (j < 3) *(uint4*)&bufIn[lidx(e, 21+j, 24)] = z4;
  }
  __syncthreads();
  f4v acc[4][2];
  f4v z = {0.f,0.f,0.f,0.f};
  // G1: ew1 (KC=5) -> silu(+eb1) -> bufA
  #pragma unroll
  for (int et=0;et<4;et++){ acc[et][0]=z; acc[et][1]=z; }
  gemm_rm<5,24>(bufIn, wfrag + 0, wu, lane, acc);
  epi_rm<16,true,true>(bufA, acc, eb1, wu, lane);
  __syncthreads();
  // G2: ew2 (KC=4) -> ef(+eb2) -> bufIn chunks 0..15
  #pragma unroll
  for (int et=0;et<4;et++){ acc[et][0]=z; acc[et][1]=z; }
  gemm_rm<4,16>(bufA, wfrag + 20480, wu, lane, acc);
  epi_rm<24,false,true>(bufIn, acc, eb2, wu, lane);
  __syncthreads();
  // eww: wave wu = head wu, full 128-dot per edge, plain store (no atomics)
  ewt2_s[wu*65+lane] = dot128<24>(bufIn, wu, lane, eww);
  __syncthreads();
  {
    int e2 = t>>2, hh = t&3;
    float lg = logit_s[t] + ewt_s[t] + ewt2_s[hh*65+e2];
    float ex = __expf(lg);
    eattn[(size_t)ebase*4 + t] = ex;
    atomicAdd(&asum[row_s[e2]*4 + hh], ex);
  }
}

// ---------------- E2: recompute ef + message MLP + heads (MFMA, row-major LDS) ----------------
__global__ __launch_bounds__(256) void k_e2(
    const float* __restrict__ h, const float* __restrict__ x, const int* __restrict__ ei,
    const float* __restrict__ stats,
    const float* __restrict__ asum, float* __restrict__ eattn,
    const unsigned short* __restrict__ wfrag,
    const float* __restrict__ eb1, const float* __restrict__ eb2,
    const float* __restrict__ mb1, const float* __restrict__ mb2,
    const float* __restrict__ gw, const float* __restrict__ gb,
    const float* __restrict__ cb1, const float* __restrict__ cw2, const float* __restrict__ cb2,
    const float* __restrict__ coordw,
    const float* __restrict__ xb1, const float* __restrict__ xw2, const float* __restrict__ xb2,
    float* __restrict__ cvec){
  __shared__ __align__(16) unsigned short bufIn[64*24*8];
  __shared__ __align__(16) unsigned short bufA [64*16*8];
  __shared__ float attn_s[256];
  __shared__ float g_s[4*65], c_s[4*65], xx_s[4*65];   // [h][e], plain stores
  __shared__ float s_s[64], cs_s[64];
  __shared__ float rp_s[192], rd_s[64], xnr_s[192], xnc_s[192], xc_s[192];
  __shared__ int row_s[64], col_s[64];
  int t = threadIdx.x; int lane = t & 63; int w = t >> 6;
  int wu = __builtin_amdgcn_readfirstlane(w);
  int ebase = blockIdx.x * 64;

  if (t < 64){
    int ge = ebase + t;
    int r = ei[ge], c = ei[NE+ge];
    row_s[t]=r; col_s[t]=c;
    float xr0=x[r*3],xr1=x[r*3+1],xr2=x[r*3+2];
    float xc0=x[c*3],xc1=x[c*3+1],xc2=x[c*3+2];
    float rp0=xr0-xc0, rp1=xr1-xc1, rp2=xr2-xc2;
    rp_s[t*3+0]=rp0; rp_s[t*3+1]=rp1; rp_s[t*3+2]=rp2;
    rd_s[t]=rp0*rp0+rp1*rp1+rp2*rp2;
    xc_s[t*3+0]=xc0; xc_s[t*3+1]=xc1; xc_s[t*3+2]=xc2;
    float m0=stats[6],m1=stats[7],m2=stats[8],s0=stats[9],s1=stats[10],s2=stats[11];
    xnr_s[t*3+0]=(xr0-m0)*s0; xnr_s[t*3+1]=(xr1-m1)*s1; xnr_s[t*3+2]=(xr2-m2)*s2;
    xnc_s[t*3+0]=(xc0-m0)*s0; xnc_s[t*3+1]=(xc1-m1)*s1; xnc_s[t*3+2]=(xc2-m2)*s2;
  }
  __syncthreads();
  // attn normalize (write back for k_aggout)
  {
    int e2 = t>>2; int hh = t&3;
    float ex = eattn[(size_t)ebase*4 + t];
    float a = ex / (asum[row_s[e2]*4 + hh] + 1e-8f);
    attn_s[t]=a;
    eattn[(size_t)ebase*4 + t]=a;
  }
  // stage row-major input (same as k_e1)
  {
    const float* hr = h + (size_t)row_s[lane]*64 + wu*16;
    pack8(&bufIn[lidx(lane, 2*wu,   24)], *(const float4*)(hr),   *(const float4*)(hr+4));
    pack8(&bufIn[lidx(lane, 2*wu+1, 24)], *(const float4*)(hr+8), *(const float4*)(hr+12));
    const float* hc = h + (size_t)col_s[lane]*64 + wu*16;
    pack8(&bufIn[lidx(lane, 8+2*wu, 24)], *(const float4*)(hc),   *(const float4*)(hc+4));
    pack8(&bufIn[lidx(lane, 9+2*wu, 24)], *(const float4*)(hc+8), *(const float4*)(hc+12));
  }
  if (t < 64){
    pack8(&bufIn[lidx(t,16,24)],
          make_float4(rd_s[t], xnr_s[t*3+0], xnr_s[t*3+1], xnr_s[t*3+2]),
          make_float4(xnc_s[t*3+0], xnc_s[t*3+1], xnc_s[t*3+2], 0.f));
  }
  {
    uint4 z4 = make_uint4(0,0,0,0);
    int e = t&63, j = t>>6;
    *(uint4*)&bufIn[lidx(e, 17+j, 24)] = z4;
    if (j < 3) *(uint4*)&bufIn[lidx(e, 21+j, 24)] = z4;
  }
  __syncthreads();
  f4v acc[4][2];
  f4v z = {0.f,0.f,0.f,0.f};
  // G1: ew1 -> silu -> bufA
  #pragma unroll
  for (int et=0;et<4;et++){ acc[et][0]=z; acc[et][1]=z; }
  gemm_rm<5,24>(bufIn, wfrag + 0, wu, lane, acc);
  epi_rm<16,true,true>(bufA, acc, eb1, wu, lane);
  __syncthreads();
  // G2: ew2 -> ef -> bufIn chunks 0..15; rewrite extras (chunks 16,17) for mw1
  #pragma unroll
  for (int et=0;et<4;et++){ acc[et][0]=z; acc[et][1]=z; }
  gemm_rm<4,16>(bufA, wfrag + 20480, wu, lane, acc);
  epi_rm<24,false,true>(bufIn, acc, eb2, wu, lane);
  if (t < 64){
    float am = 0.25f*(attn_s[t*4]+attn_s[t*4+1]+attn_s[t*4+2]+attn_s[t*4+3]);
    pack8(&bufIn[lidx(t,16,24)],
          make_float4(am, rp_s[t*3+0], rp_s[t*3+1], rp_s[t*3+2]),
          make_float4(xnr_s[t*3+0], xnr_s[t*3+1], xnr_s[t*3+2], xnc_s[t*3+0]));
    pack8(&bufIn[lidx(t,17,24)],
          make_float4(xnc_s[t*3+1], xnc_s[t*3+2], 0.f, 0.f),
          make_float4(0.f,0.f,0.f,0.f));
  }
  __syncthreads();
  // G3: mw1 (KC=5) -> silu -> bufA
  #pragma unroll
  for (int et=0;et<4;et++){ acc[et][0]=z; acc[et][1]=z; }
  gemm_rm<5,24>(bufIn, wfrag + 36864, wu, lane, acc);
  epi_rm<16,true,true>(bufA, acc, mb1, wu, lane);
  __syncthreads();
  // G4: mw2 -> msgs(+mb2) -> bufIn chunks 0..15
  #pragma unroll
  for (int et=0;et<4;et++){ acc[et][0]=z; acc[et][1]=z; }
  gemm_rm<4,16>(bufA, wfrag + 57344, wu, lane, acc);
  epi_rm<24,false,true>(bufIn, acc, mb2, wu, lane);
  __syncthreads();
  // gates: wave wu = head wu, full dot, plain store (no atomics)
  g_s[wu*65+lane] = dot128<24>(bufIn, wu, lane, gw);
  // G5+G6: cw1 & xw1 from msgs (share B loads)
  f4v ax[4][2];
  #pragma unroll
  for (int et=0;et<4;et++){ acc[et][0]=z; acc[et][1]=z; ax[et][0]=z; ax[et][1]=z; }
  {
    const unsigned short* wfc = wfrag + 73728;
    const unsigned short* wfx = wfrag + 90112;
    int le = lane&15, quad = lane>>4;
    #pragma unroll
    for (int kc=0;kc<4;kc++){
      bf16x8 ac0 = *(const bf16x8*)(wfc + (((wu*2  )*4 + kc)<<9) + lane*8);
      bf16x8 ac1 = *(const bf16x8*)(wfc + (((wu*2+1)*4 + kc)<<9) + lane*8);
      bf16x8 ax0 = *(const bf16x8*)(wfx + (((wu*2  )*4 + kc)<<9) + lane*8);
      bf16x8 ax1 = *(const bf16x8*)(wfx + (((wu*2+1)*4 + kc)<<9) + lane*8);
      int chunk = kc*4 + quad;
      #pragma unroll
      for (int et=0;et<4;et++){
        bf16x8 b = *(const bf16x8*)(bufIn + lidx(et*16+le, chunk, 24));
        acc[et][0] = __builtin_amdgcn_mfma_f32_16x16x32_bf16(ac0, b, acc[et][0], 0,0,0);
        acc[et][1] = __builtin_amdgcn_mfma_f32_16x16x32_bf16(ac1, b, acc[et][1], 0,0,0);
        ax[et][0]  = __builtin_amdgcn_mfma_f32_16x16x32_bf16(ax0, b, ax[et][0], 0,0,0);
        ax[et][1]  = __builtin_amdgcn_mfma_f32_16x16x32_bf16(ax1, b, ax[et][1], 0,0,0);
      }
    }
  }
  __syncthreads();   // all waves done reading bufA (G4) & bufIn (G5/6 + gw)
  epi_rm<16,true,true>(bufA, acc, cb1, wu, lane);   // silu(cpre+cb1)
  __syncthreads();
  c_s[wu*65+lane] = dot128<16>(bufA, wu, lane, cw2);
  __syncthreads();
  epi_rm<16,true,true>(bufA, ax, xb1, wu, lane);    // silu(xpre+xb1)
  __syncthreads();
  xx_s[wu*65+lane] = dot128<16>(bufA, wu, lane, xw2);
  __syncthreads();
  // combine heads: shfl reduction over the 4 consecutive lanes of each edge group
  {
    int e2 = t>>2; int hh = t&3;
    float g = 1.0f/(1.0f+__expf(-(g_s[hh*65+e2]+gb[hh])));
    float cwv = c_s[hh*65+e2]+cb2[hh];
    float sv = g*cwv*coordw[hh];
    float csv = xx_s[hh*65+e2]+xb2[hh];
    sv += __shfl_xor(sv,1);  sv += __shfl_xor(sv,2);
    csv += __shfl_xor(csv,1); csv += __shfl_xor(csv,2);
    if (hh==0){ s_s[e2]=sv; cs_s[e2]=csv; }
  }
  __syncthreads();
  if (t < 64){
    int ge = ebase + t;
    float rp0=rp_s[t*3],rp1=rp_s[t*3+1],rp2=rp_s[t*3+2];
    float pp0,pp1,pp2;
    if (t > 0){ pp0=rp_s[(t-1)*3]; pp1=rp_s[(t-1)*3+1]; pp2=rp_s[(t-1)*3+2]; }
    else {
      int gp = (ebase==0)? (NE-1) : (ebase-1);
      int rr=ei[gp], cc2=ei[NE+gp];
      pp0=x[rr*3]-x[cc2*3]; pp1=x[rr*3+1]-x[cc2*3+1]; pp2=x[rr*3+2]-x[cc2*3+2];
    }
    float cv0 = rp1*pp2 - rp2*pp1;
    float cv1 = rp2*pp0 - rp0*pp2;
    float cv2 = rp0*pp1 - rp1*pp0;
    float sv = s_s[t], csv = cs_s[t];
    const float inv = 1.0f/49999.0f;
    cvec[(size_t)ge*3+0] = (sv*(0.9f*rp0+0.1f*xc_s[t*3+0]) + csv*cv0)*inv;
    cvec[(size_t)ge*3+1] = (sv*(0.9f*rp1+0.1f*xc_s[t*3+1]) + csv*cv1)*inv;
    cvec[(size_t)ge*3+2] = (sv*(0.9f*rp2+0.1f*xc_s[t*3+2]) + csv*cv2)*inv;
  }
}

// ---------------- fused aggregation + out GEMM: one wave per node ----------------
__global__ __launch_bounds__(256) void k_aggout(
    const int* __restrict__ ei, const int* __restrict__ offs, const int* __restrict__ elist,
    const float* __restrict__ eattn, const unsigned short* __restrict__ vb,
    const float* __restrict__ cvec, const float* __restrict__ Wo, const float* __restrict__ bo,
    float* __restrict__ outp){
  __shared__ float wvs[4*256];
  int t = threadIdx.x; int lane = t & 63; int w = t >> 6;
  int node = blockIdx.x*4 + w;
  const int* colp = ei + NE;
  int s0 = offs[node], s1 = offs[node+1];
  float a0=0,a1=0,a2=0,a3=0,cc=0;
  int i = s0;
  for (; i+4<=s1; i+=4){
    int e0=elist[i], e1=elist[i+1], e2=elist[i+2], e3=elist[i+3];
    int c0=colp[e0], c1=colp[e1], c2=colp[e2], c3=colp[e3];
    uint2 v0 = *(const uint2*)(vb + (size_t)c0*256 + lane*4);
    uint2 v1 = *(const uint2*)(vb + (size_t)c1*256 + lane*4);
    uint2 v2 = *(const uint2*)(vb + (size_t)c2*256 + lane*4);
    uint2 v3 = *(const uint2*)(vb + (size_t)c3*256 + lane*4);
    float4 at0 = *(const float4*)(eattn + (size_t)e0*4);
    float4 at1 = *(const float4*)(eattn + (size_t)e1*4);
    float4 at2 = *(const float4*)(eattn + (size_t)e2*4);
    float4 at3 = *(const float4*)(eattn + (size_t)e3*4);
    if (lane < 3) cc += cvec[(size_t)e0*3+lane] + cvec[(size_t)e1*3+lane]
                      + cvec[(size_t)e2*3+lane] + cvec[(size_t)e3*3+lane];
    a0 += at0.x*bf2f(v0.x&0xffffu) + at1.x*bf2f(v1.x&0xffffu) + at2.x*bf2f(v2.x&0xffffu) + at3.x*bf2f(v3.x&0xffffu);
    a1 += at0.y*bf2f(v0.x>>16)     + at1.y*bf2f(v1.x>>16)     + at2.y*bf2f(v2.x>>16)     + at3.y*bf2f(v3.x>>16);
    a2 += at0.z*bf2f(v0.y&0xffffu) + at1.z*bf2f(v1.y&0xffffu) + at2.z*bf2f(v2.y&0xffffu) + at3.z*bf2f(v3.y&0xffffu);
    a3 += at0.w*bf2f(v0.y>>16)     + at1.w*bf2f(v1.y>>16)     + at2.w*bf2f(v2.y>>16)     + at3.w*bf2f(v3.y>>16);
  }
  for (; i<s1; i++){
    int e0 = elist[i];
    int c0 = colp[e0];
    uint2 v0 = *(const uint2*)(vb + (size_t)c0*256 + lane*4);
    float4 at0 = *(const float4*)(eattn + (size_t)e0*4);
    if (lane < 3) cc += cvec[(size_t)e0*3+lane];
    a0 += at0.x*bf2f(v0.x&0xffffu);
    a1 += at0.y*bf2f(v0.x>>16);
    a2 += at0.z*bf2f(v0.y&0xffffu);
    a3 += at0.w*bf2f(v0.y>>16);
  }
  wvs[w*256 +       lane]=a0;
  wvs[w*256 +  64 + lane]=a1;
  wvs[w*256 + 128 + lane]=a2;
  wvs[w*256 + 192 + lane]=a3;
  if (lane < 3) outp[(size_t)NN*64 + (size_t)node*3 + lane] = cc;
  float o = bo[lane];
  #pragma unroll 4
  for (int k2=0;k2<256;k2++) o += wvs[w*256+k2] * Wo[k2*64+lane];
  outp[(size_t)node*64 + lane] = o;
}

extern "C" void kernel_launch(void* const* d_in, const int* in_sizes, int n_in,
                              void* d_out, int out_size, void* d_ws, size_t ws_size,
                              hipStream_t stream) {
  const float* h  = (const float*)d_in[0];
  const float* x  = (const float*)d_in[1];
  const int*   ei = (const int*)d_in[2];
  // d_in[3] = mask (all true)
  const float* Wq=(const float*)d_in[4];  const float* bq=(const float*)d_in[5];
  const float* Wk=(const float*)d_in[6];  const float* bk=(const float*)d_in[7];
  const float* Wv=(const float*)d_in[8];  const float* bv=(const float*)d_in[9];
  const float* Wo=(const float*)d_in[10]; const float* bo=(const float*)d_in[11];
  const float* pw1=(const float*)d_in[12]; const float* pb1=(const float*)d_in[13];
  const float* pw2=(const float*)d_in[14]; const float* pb2=(const float*)d_in[15];
  const float* ew1=(const float*)d_in[16]; const float* eb1=(const float*)d_in[17];
  const float* ew2=(const float*)d_in[18]; const float* eb2=(const float*)d_in[19];
  const float* eww=(const float*)d_in[20]; const float* ewb=(const float*)d_in[21];
  const float* mw1=(const float*)d_in[22]; const float* mb1=(const float*)d_in[23];
  const float* mw2=(const float*)d_in[24]; const float* mb2=(const float*)d_in[25];
  const float* gw=(const float*)d_in[26];  const float* gb=(const float*)d_in[27];
  const float* cw1=(const float*)d_in[28]; const float* cb1=(const float*)d_in[29];
  const float* cw2=(const float*)d_in[30]; const float* cb2=(const float*)d_in[31];
  const float* coordw=(const float*)d_in[32];
  const float* xw1=(const float*)d_in[33]; const float* xb1=(const float*)d_in[34];
  const float* xw2=(const float*)d_in[35]; const float* xb2=(const float*)d_in[36];

  // workspace layout (bytes), high-water = 103,813,088
  char* B = (char*)d_ws;
  float* eattn = (float*)(B + 0);                        // E*4*4   = 12,800,000
  float* cvec  = (float*)(B + 12800000);                 // E*3*4   =  9,600,000
  float* stats = (float*)(B + 22400000);                 // 64
  float* asum  = (float*)(B + 22400064);                 // N*4*4   =    800,000
  int* counts  = (int*)(B + 23200064);                   // N*4     =    200,000  (also cursor)
  int* offs    = (int*)(B + 23400064);                   // (N+1)*4 =    200,004
  unsigned short* wfrag = (unsigned short*)(B + 23600080); // 106,496 bf16 = 212,992
  int* elist   = (int*)(B + 23813088);                   // E*4     =  3,200,000
  unsigned short* qb = (unsigned short*)(B + 27013088);  // N*256*2 = 25,600,000
  unsigned short* kb = (unsigned short*)(B + 52613088);  // N*256*2 = 25,600,000
  unsigned short* vb = (unsigned short*)(B + 78213088);  // N*256*2 = 25,600,000

  // zero stats+asum+counts (contiguous 1,000,064 B)
  k_zero<<<977,256,0,stream>>>(stats, 250016);
  // weight fragment prep (bf16, MFMA A-frag layout)
  k_wprep<<<80,256,0,stream>>>(ew1, wfrag + 0,     135, 5);
  k_wprep<<<64,256,0,stream>>>(ew2, wfrag + 20480, 128, 4);
  k_wprep<<<80,256,0,stream>>>(mw1, wfrag + 36864, 138, 5);
  k_wprep<<<64,256,0,stream>>>(mw2, wfrag + 57344, 128, 4);
  k_wprep<<<64,256,0,stream>>>(cw1, wfrag + 73728, 128, 4);
  k_wprep<<<64,256,0,stream>>>(xw1, wfrag + 90112, 128, 4);

  k_stats<<<196,256,0,stream>>>(x, stats);
  k_statsfin<<<1,64,0,stream>>>(stats);
  k_qkv<<<dim3(1563,12),256,0,stream>>>(h,Wq,bq,Wk,bk,Wv,bv,qb,kb,vb);
  k_count<<<3125,256,0,stream>>>(ei,counts);
  k_scan<<<1,256,0,stream>>>(counts,offs);
  k_fill<<<3125,256,0,stream>>>(ei,counts,elist);
  k_e1<<<12500,256,0,stream>>>(h,x,ei,stats,qb,kb,wfrag,eb1,eb2,eww,ewb,pw1,pb1,pw2,pb2,asum,eattn);
  k_e2<<<12500,256,0,stream>>>(h,x,ei,stats,asum,eattn,wfrag,eb1,eb2,mb1,mb2,gw,gb,cb1,cw2,cb2,coordw,xb1,xw2,xb2,cvec);
  k_aggout<<<12500,256,0,stream>>>(ei,offs,elist,eattn,vb,cvec,Wo,bo,(float*)d_out);
}

// Round 9
// 1747.519 us; speedup vs baseline: 1.1602x; 1.0397x over previous
//
#include <hip/hip_runtime.h>
#include <hip/hip_bf16.h>

#define NN 50000
#define NE 800000

typedef __bf16 bf16x8 __attribute__((ext_vector_type(8)));
typedef float f4v __attribute__((ext_vector_type(4)));

__device__ __forceinline__ float silu_f(float v){ return v/(1.0f+__expf(-v)); }
__device__ __forceinline__ float bf2f(unsigned int u){ return __uint_as_float(u<<16); }
__device__ __forceinline__ unsigned short f2bf(float f){ __hip_bfloat16 b=__float2bfloat16(f); return *reinterpret_cast<unsigned short*>(&b); }
__device__ __forceinline__ unsigned pk2(float a, float b){ return (unsigned)f2bf(a) | ((unsigned)f2bf(b)<<16); }

union U8 { unsigned short us[8]; uint4 u4; };

__device__ __forceinline__ void pack8(unsigned short* dst, float4 a, float4 b){
  uint4 u;
  u.x = pk2(a.x,a.y); u.y = pk2(a.z,a.w);
  u.z = pk2(b.x,b.y); u.w = pk2(b.z,b.w);
  *(uint4*)dst = u;
}

// short-index of 16B chunk c of row e in a row-major swizzled activation buffer
// (CH = chunks per row, multiple of 8; chunk swizzled within its group of 8)
__device__ __forceinline__ int lidx(int e, int c, int CH){
  return (e*CH + ((c & ~7) | ((c ^ e) & 7))) << 3;
}

// GEMM: A = weights (global frag order), B = activations (row-major swizzled LDS).
// acc[et][ot]: D rows = outcols (wu*32+ot*16+quad*4+r), cols = edges (et*16+(lane&15)).
template<int KC, int CH>
__device__ __forceinline__ void gemm_rm(const unsigned short* act, const unsigned short* wf,
                                        int wu, int lane, f4v (&acc)[4][2]){
  int le = lane & 15, quad = lane >> 4;
  #pragma unroll
  for (int kc=0;kc<KC;kc++){
    bf16x8 a0 = *(const bf16x8*)(wf + (((wu*2  )*KC + kc)<<9) + lane*8);
    bf16x8 a1 = *(const bf16x8*)(wf + (((wu*2+1)*KC + kc)<<9) + lane*8);
    int chunk = kc*4 + quad;
    #pragma unroll
    for (int et=0;et<4;et++){
      bf16x8 b = *(const bf16x8*)(act + lidx(et*16+le, chunk, CH));
      acc[et][0] = __builtin_amdgcn_mfma_f32_16x16x32_bf16(a0, b, acc[et][0], 0,0,0);
      acc[et][1] = __builtin_amdgcn_mfma_f32_16x16x32_bf16(a1, b, acc[et][1], 0,0,0);
    }
  }
}

// epilogue: D regs -> row-major swizzled bf16 buffer, packed b64 stores
template<int CH, bool SILU, bool BIAS>
__device__ __forceinline__ void epi_rm(unsigned short* dst, const f4v (&acc)[4][2],
                                       const float* bias, int wu, int lane){
  int le = lane & 15, quad = lane >> 4;
  #pragma unroll
  for (int ot=0; ot<2; ot++){
    float4 bv = make_float4(0,0,0,0);
    if (BIAS) bv = *(const float4*)(bias + wu*32 + ot*16 + quad*4);
    int chunk = wu*4 + ot*2 + (quad>>1);
    int soff = (quad&1)*4;
    #pragma unroll
    for (int et=0; et<4; et++){
      float v0=acc[et][ot][0], v1=acc[et][ot][1], v2=acc[et][ot][2], v3=acc[et][ot][3];
      if (BIAS){ v0+=bv.x; v1+=bv.y; v2+=bv.z; v3+=bv.w; }
      if (SILU){ v0=silu_f(v0); v1=silu_f(v1); v2=silu_f(v2); v3=silu_f(v3); }
      uint2 u; u.x = pk2(v0,v1); u.y = pk2(v2,v3);
      *(uint2*)(dst + lidx(et*16+le, chunk, CH) + soff) = u;
    }
  }
}

// head reduction as MFMA: out[h][e] = sum_k W[k][h]*act[e][k], h=0..3 (padded to 16).
// Wave wu covers edges wu*16..wu*16+15. whf = [KC=4][512] A-frag of W^T.
// D: row=quad*4+r -> head (rows 0..3 live in quad 0), col=le -> edge.
template<int CH>
__device__ __forceinline__ void mfma_head(const unsigned short* buf, const unsigned short* whf,
                                          int wu, int lane, float* dst /*[4*65]*/){
  int le = lane & 15, quad = lane >> 4;
  f4v hacc = {0.f,0.f,0.f,0.f};
  #pragma unroll
  for (int kc=0;kc<4;kc++){
    bf16x8 a = *(const bf16x8*)(whf + (kc<<9) + lane*8);
    bf16x8 b = *(const bf16x8*)(buf + lidx(wu*16+le, kc*4+quad, CH));
    hacc = __builtin_amdgcn_mfma_f32_16x16x32_bf16(a, b, hacc, 0,0,0);
  }
  if (quad==0){
    #pragma unroll
    for (int r=0;r<4;r++) dst[r*65 + wu*16 + le] = hacc[r];
  }
}

// ---------------- zero a span ----------------
__global__ __launch_bounds__(256) void k_zero(float* __restrict__ p, int n){
  int i = blockIdx.x*256 + threadIdx.x;
  if (i < n) p[i] = 0.f;
}

// ---------------- weight pre-pack into MFMA fragment order (bf16) ----------------
__global__ __launch_bounds__(256) void k_wprep(const float* __restrict__ src, unsigned short* __restrict__ dst,
                                               int Kreal, int KC){
  int idx = blockIdx.x*256 + threadIdx.x;
  int tot = 8*KC*512;
  if (idx >= tot) return;
  int nt  = idx/(KC*512); int rem = idx%(KC*512);
  int kc  = rem>>9;       int r2  = rem&511;
  int lq  = r2>>3;        int j   = r2&7;
  int k   = kc*32 + (lq>>4)*8 + j;
  int n   = nt*16 + (lq&15);
  float v = (k < Kreal) ? src[k*128 + n] : 0.f;
  dst[idx] = f2bf(v);
}

// head-matrix [128][4] -> A-frag (M padded 4->16), KC=4, 2048 shorts
__global__ __launch_bounds__(256) void k_wprep4(const float* __restrict__ src, unsigned short* __restrict__ dst){
  int idx = blockIdx.x*256 + threadIdx.x;
  if (idx >= 2048) return;
  int kc = idx>>9; int r2 = idx&511; int lq = r2>>3; int j = r2&7;
  int k = kc*32 + (lq>>4)*8 + j;
  int n = lq&15;
  dst[idx] = f2bf((n<4) ? src[k*4+n] : 0.f);
}

// ---------------- stats ----------------
__global__ __launch_bounds__(256) void k_stats(const float* __restrict__ x, float* __restrict__ stats){
  int i = blockIdx.x*256 + threadIdx.x;
  float v0=0.f,v1=0.f,v2=0.f;
  if (i < NN){ v0=x[i*3+0]; v1=x[i*3+1]; v2=x[i*3+2]; }
  float vals[6] = {v0,v1,v2,v0*v0,v1*v1,v2*v2};
  __shared__ float red[256];
  for (int c=0;c<6;c++){
    red[threadIdx.x]=vals[c];
    __syncthreads();
    for (int off=128; off>0; off>>=1){
      if (threadIdx.x < off) red[threadIdx.x] += red[threadIdx.x+off];
      __syncthreads();
    }
    if (threadIdx.x==0) atomicAdd(&stats[c], red[0]);
    __syncthreads();
  }
}

__global__ __launch_bounds__(64) void k_statsfin(float* __restrict__ stats){
  int t = threadIdx.x;
  if (t < 3){
    float s = stats[t], sq = stats[3+t];
    float mean = s/(float)NN;
    float var = (sq - s*s/(float)NN)/(float)(NN-1);
    float sd = sqrtf(var);
    stats[6+t] = mean;
    stats[9+t] = 1.0f/(sd + 1e-8f);
  }
}

// ---------------- q,k,v = h @ W + b  (bf16 out; v stored [node][d][head]) ----------------
__global__ __launch_bounds__(256) void k_qkv(const float* __restrict__ h,
    const float* __restrict__ Wq, const float* __restrict__ bq,
    const float* __restrict__ Wk, const float* __restrict__ bk,
    const float* __restrict__ Wv, const float* __restrict__ bv,
    unsigned short* __restrict__ q, unsigned short* __restrict__ kk, unsigned short* __restrict__ v){
  __shared__ float hs[32*68];
  int t = threadIdx.x;
  int by = blockIdx.y;
  int mat = by>>2; int quarter = by&3; int colbase = quarter*64;
  const float* W; const float* bb; unsigned short* outp;
  if (mat==0){W=Wq;bb=bq;outp=q;} else if (mat==1){W=Wk;bb=bk;outp=kk;} else {W=Wv;bb=bv;outp=v;}
  int r0 = blockIdx.x*32;
  {
    int rw = t>>3; int c0 = (t&7)*8;
    int row = r0 + rw;
    float4 a = make_float4(0,0,0,0), b2 = make_float4(0,0,0,0);
    if (row < NN){
      a  = *(const float4*)(h + (size_t)row*64 + c0);
      b2 = *(const float4*)(h + (size_t)row*64 + c0 + 4);
    }
    *(float4*)(&hs[rw*68 + c0])     = a;
    *(float4*)(&hs[rw*68 + c0 + 4]) = b2;
  }
  __syncthreads();
  int rg = t>>3; int cg = t&7; int col = colbase + cg*8;
  float acc[8];
  #pragma unroll
  for (int j=0;j<8;j++) acc[j]=0.f;
  for (int k2=0;k2<64;k2++){
    float a = hs[rg*68 + k2];
    const float4 w0 = *(const float4*)(W + k2*256 + col);
    const float4 w1 = *(const float4*)(W + k2*256 + col + 4);
    acc[0]+=a*w0.x; acc[1]+=a*w0.y; acc[2]+=a*w0.z; acc[3]+=a*w0.w;
    acc[4]+=a*w1.x; acc[5]+=a*w1.y; acc[6]+=a*w1.z; acc[7]+=a*w1.w;
  }
  int row = r0 + rg;
  if (row < NN){
    if (mat==2){
      #pragma unroll
      for (int j=0;j<8;j++) outp[(size_t)row*256 + (size_t)(cg*8+j)*4 + quarter] = f2bf(acc[j]+bb[col+j]);
    } else {
      U8 u;
      #pragma unroll
      for (int j=0;j<8;j++) u.us[j] = f2bf(acc[j]+bb[col+j]);
      *(uint4*)(outp + (size_t)row*256 + col) = u.u4;
    }
  }
}

// ---------------- CSR build ----------------
__global__ __launch_bounds__(256) void k_count(const int* __restrict__ ei, int* __restrict__ counts){
  int e = blockIdx.x*256 + threadIdx.x;
  if (e < NE) atomicAdd(&counts[ei[e]], 1);
}

__global__ __launch_bounds__(256) void k_scan(int* __restrict__ counts, int* __restrict__ offs){
  __shared__ int ps[256];
  int t = threadIdx.x;
  int base = t*196;
  int s = 0;
  for (int i=0;i<196;i++){ int idx = base+i; if (idx < NN) s += counts[idx]; }
  ps[t]=s; __syncthreads();
  for (int off=1; off<256; off<<=1){
    int vv = (t>=off)? ps[t-off] : 0;
    __syncthreads();
    ps[t]+=vv;
    __syncthreads();
  }
  int run = ps[t]-s;
  for (int i=0;i<196;i++){
    int idx = base+i;
    if (idx < NN){ int c = counts[idx]; offs[idx]=run; counts[idx]=run; run+=c; }
  }
  if (t==255) offs[NN]=run;
}

__global__ __launch_bounds__(256) void k_fill(const int* __restrict__ ei, int* __restrict__ cursor, int* __restrict__ elist){
  int e = blockIdx.x*256 + threadIdx.x;
  if (e < NE){
    int r = ei[e];
    int p = atomicAdd(&cursor[r],1);
    elist[p] = e;
  }
}

// ---------------- E1: edge MLP (MFMA, row-major LDS) + attention logits ----------------
__global__ __launch_bounds__(256) void k_e1(
    const float* __restrict__ h, const float* __restrict__ x, const int* __restrict__ ei,
    const float* __restrict__ stats,
    const unsigned short* __restrict__ qb, const unsigned short* __restrict__ kb,
    const unsigned short* __restrict__ wfrag, const unsigned short* __restrict__ whfrag,
    const float* __restrict__ eb1, const float* __restrict__ eb2,
    const float* __restrict__ ewb,
    const float* __restrict__ pw1, const float* __restrict__ pb1,
    const float* __restrict__ pw2, const float* __restrict__ pb2,
    float* __restrict__ asum, float* __restrict__ eattn){
  __shared__ __align__(16) unsigned short bufIn[64*24*8];  // K<=192 row-major swizzled
  __shared__ __align__(16) unsigned short bufA [64*16*8];  // K=128
  __shared__ float ewt_s[256], logit_s[256];
  __shared__ float ewt2_s[4*65];   // [h][e]: eww head dots (unique writer per slot)
  __shared__ float rd_s[64], xnr_s[192], xnc_s[192];
  __shared__ int row_s[64], col_s[64];
  int t = threadIdx.x; int lane = t & 63; int w = t >> 6;
  int wu = __builtin_amdgcn_readfirstlane(w);
  int ebase = blockIdx.x * 64;

  if (t < 64){
    int ge = ebase + t;
    int r = ei[ge], c = ei[NE+ge];
    row_s[t]=r; col_s[t]=c;
    float xr0=x[r*3],xr1=x[r*3+1],xr2=x[r*3+2];
    float xc0=x[c*3],xc1=x[c*3+1],xc2=x[c*3+2];
    float rp0=xr0-xc0, rp1=xr1-xc1, rp2=xr2-xc2;
    rd_s[t]=rp0*rp0+rp1*rp1+rp2*rp2;
    float m0=stats[6],m1=stats[7],m2=stats[8],s0=stats[9],s1=stats[10],s2=stats[11];
    xnr_s[t*3+0]=(xr0-m0)*s0; xnr_s[t*3+1]=(xr1-m1)*s1; xnr_s[t*3+2]=(xr2-m2)*s2;
    xnc_s[t*3+0]=(xc0-m0)*s0; xnc_s[t*3+1]=(xc1-m1)*s1; xnc_s[t*3+2]=(xc2-m2)*s2;
    #pragma unroll
    for (int hh=0;hh<4;hh++) ewt_s[t*4+hh] = ewb[hh] + pb2[hh];
  }
  __syncthreads();

  // q.k dots
  for (int ii=0; ii<16; ii++){
    int e = wu*16+ii;
    int r = row_s[e], c = col_s[e];
    uint2 qu = *(const uint2*)(qb + (size_t)r*256 + lane*4);
    uint2 ku = *(const uint2*)(kb + (size_t)c*256 + lane*4);
    float d = bf2f(qu.x&0xffffu)*bf2f(ku.x&0xffffu)
            + bf2f(qu.x>>16)   *bf2f(ku.x>>16)
            + bf2f(qu.y&0xffffu)*bf2f(ku.y&0xffffu)
            + bf2f(qu.y>>16)   *bf2f(ku.y>>16);
    d += __shfl_xor(d,1,16); d += __shfl_xor(d,2,16);
    d += __shfl_xor(d,4,16); d += __shfl_xor(d,8,16);
    if ((lane&15)==0) logit_s[e*4 + (lane>>4)] = d*0.125f;
  }
  // pos_enc partials
  {
    int jb = wu*16;
    float rd = rd_s[lane];
    float p0=0,p1=0,p2=0,p3=0;
    for (int j=jb; j<jb+16; j++){
      float hp = rd*pw1[j] + pb1[j];
      float hs = silu_f(hp);
      const float4 w4 = *(const float4*)(pw2 + j*4);
      p0+=hs*w4.x; p1+=hs*w4.y; p2+=hs*w4.z; p3+=hs*w4.w;
    }
    atomicAdd(&ewt_s[lane*4+0],p0); atomicAdd(&ewt_s[lane*4+1],p1);
    atomicAdd(&ewt_s[lane*4+2],p2); atomicAdd(&ewt_s[lane*4+3],p3);
  }
  // stage row-major: k 0..63 h[row], 64..127 h[col], 128..134 extras, rest zero
  {
    const float* hr = h + (size_t)row_s[lane]*64 + wu*16;
    pack8(&bufIn[lidx(lane, 2*wu,   24)], *(const float4*)(hr),   *(const float4*)(hr+4));
    pack8(&bufIn[lidx(lane, 2*wu+1, 24)], *(const float4*)(hr+8), *(const float4*)(hr+12));
    const float* hc = h + (size_t)col_s[lane]*64 + wu*16;
    pack8(&bufIn[lidx(lane, 8+2*wu, 24)], *(const float4*)(hc),   *(const float4*)(hc+4));
    pack8(&bufIn[lidx(lane, 9+2*wu, 24)], *(const float4*)(hc+8), *(const float4*)(hc+12));
  }
  if (t < 64){
    pack8(&bufIn[lidx(t,16,24)],
          make_float4(rd_s[t], xnr_s[t*3+0], xnr_s[t*3+1], xnr_s[t*3+2]),
          make_float4(xnc_s[t*3+0], xnc_s[t*3+1], xnc_s[t*3+2], 0.f));
  }
  {
    uint4 z4 = make_uint4(0,0,0,0);
    int e = t&63, j = t>>6;
    *(uint4*)&bufIn[lidx(e, 17+j, 24)] = z4;
    if (j < 3) *(uint4*)&bufIn[lidx(e, 21+j, 24)] = z4;
  }
  __syncthreads();
  f4v acc[4][2];
  f4v z = {0.f,0.f,0.f,0.f};
  // G1: ew1 (KC=5) -> silu(+eb1) -> bufA
  #pragma unroll
  for (int et=0;et<4;et++){ acc[et][0]=z; acc[et][1]=z; }
  gemm_rm<5,24>(bufIn, wfrag + 0, wu, lane, acc);
  epi_rm<16,true,true>(bufA, acc, eb1, wu, lane);
  __syncthreads();
  // G2: ew2 (KC=4) -> ef(+eb2) -> bufIn chunks 0..15
  #pragma unroll
  for (int et=0;et<4;et++){ acc[et][0]=z; acc[et][1]=z; }
  gemm_rm<4,16>(bufA, wfrag + 20480, wu, lane, acc);
  epi_rm<24,false,true>(bufIn, acc, eb2, wu, lane);
  __syncthreads();
  // eww head dots via MFMA (wave wu -> edges wu*16..+15, all 4 heads)
  mfma_head<24>(bufIn, whfrag + 0, wu, lane, ewt2_s);
  __syncthreads();
  {
    int e2 = t>>2, hh = t&3;
    float lg = logit_s[t] + ewt_s[t] + ewt2_s[hh*65+e2];
    float ex = __expf(lg);
    eattn[(size_t)ebase*4 + t] = ex;
    atomicAdd(&asum[row_s[e2]*4 + hh], ex);
  }
}

// ---------------- E2: recompute ef + message MLP + heads (MFMA, row-major LDS) ----------------
__global__ __launch_bounds__(256) void k_e2(
    const float* __restrict__ h, const float* __restrict__ x, const int* __restrict__ ei,
    const float* __restrict__ stats,
    const float* __restrict__ asum, float* __restrict__ eattn,
    const unsigned short* __restrict__ wfrag, const unsigned short* __restrict__ whfrag,
    const float* __restrict__ eb1, const float* __restrict__ eb2,
    const float* __restrict__ mb1, const float* __restrict__ mb2,
    const float* __restrict__ gb,
    const float* __restrict__ cb1, const float* __restrict__ cb2,
    const float* __restrict__ coordw,
    const float* __restrict__ xb1, const float* __restrict__ xb2,
    float* __restrict__ cvec){
  __shared__ __align__(16) unsigned short bufIn[64*24*8];
  __shared__ __align__(16) unsigned short bufA [64*16*8];
  __shared__ float attn_s[256];
  __shared__ float g_s[4*65], c_s[4*65], xx_s[4*65];   // [h][e], unique writer per slot
  __shared__ float s_s[64], cs_s[64];
  __shared__ float rp_s[192], rd_s[64], xnr_s[192], xnc_s[192], xc_s[192];
  __shared__ int row_s[64], col_s[64];
  int t = threadIdx.x; int lane = t & 63; int w = t >> 6;
  int wu = __builtin_amdgcn_readfirstlane(w);
  int ebase = blockIdx.x * 64;

  if (t < 64){
    int ge = ebase + t;
    int r = ei[ge], c = ei[NE+ge];
    row_s[t]=r; col_s[t]=c;
    float xr0=x[r*3],xr1=x[r*3+1],xr2=x[r*3+2];
    float xc0=x[c*3],xc1=x[c*3+1],xc2=x[c*3+2];
    float rp0=xr0-xc0, rp1=xr1-xc1, rp2=xr2-xc2;
    rp_s[t*3+0]=rp0; rp_s[t*3+1]=rp1; rp_s[t*3+2]=rp2;
    rd_s[t]=rp0*rp0+rp1*rp1+rp2*rp2;
    xc_s[t*3+0]=xc0; xc_s[t*3+1]=xc1; xc_s[t*3+2]=xc2;
    float m0=stats[6],m1=stats[7],m2=stats[8],s0=stats[9],s1=stats[10],s2=stats[11];
    xnr_s[t*3+0]=(xr0-m0)*s0; xnr_s[t*3+1]=(xr1-m1)*s1; xnr_s[t*3+2]=(xr2-m2)*s2;
    xnc_s[t*3+0]=(xc0-m0)*s0; xnc_s[t*3+1]=(xc1-m1)*s1; xnc_s[t*3+2]=(xc2-m2)*s2;
  }
  __syncthreads();
  // attn normalize (write back for k_aggout)
  {
    int e2 = t>>2; int hh = t&3;
    float ex = eattn[(size_t)ebase*4 + t];
    float a = ex / (asum[row_s[e2]*4 + hh] + 1e-8f);
    attn_s[t]=a;
    eattn[(size_t)ebase*4 + t]=a;
  }
  // stage row-major input (same as k_e1)
  {
    const float* hr = h + (size_t)row_s[lane]*64 + wu*16;
    pack8(&bufIn[lidx(lane, 2*wu,   24)], *(const float4*)(hr),   *(const float4*)(hr+4));
    pack8(&bufIn[lidx(lane, 2*wu+1, 24)], *(const float4*)(hr+8), *(const float4*)(hr+12));
    const float* hc = h + (size_t)col_s[lane]*64 + wu*16;
    pack8(&bufIn[lidx(lane, 8+2*wu, 24)], *(const float4*)(hc),   *(const float4*)(hc+4));
    pack8(&bufIn[lidx(lane, 9+2*wu, 24)], *(const float4*)(hc+8), *(const float4*)(hc+12));
  }
  if (t < 64){
    pack8(&bufIn[lidx(t,16,24)],
          make_float4(rd_s[t], xnr_s[t*3+0], xnr_s[t*3+1], xnr_s[t*3+2]),
          make_float4(xnc_s[t*3+0], xnc_s[t*3+1], xnc_s[t*3+2], 0.f));
  }
  {
    uint4 z4 = make_uint4(0,0,0,0);
    int e = t&63, j = t>>6;
    *(uint4*)&bufIn[lidx(e, 17+j, 24)] = z4;
    if (j < 3) *(uint4*)&bufIn[lidx(e, 21+j, 24)] = z4;
  }
  __syncthreads();
  f4v acc[4][2];
  f4v z = {0.f,0.f,0.f,0.f};
  // G1: ew1 -> silu -> bufA
  #pragma unroll
  for (int et=0;et<4;et++){ acc[et][0]=z; acc[et][1]=z; }
  gemm_rm<5,24>(bufIn, wfrag + 0, wu, lane, acc);
  epi_rm<16,true,true>(bufA, acc, eb1, wu, lane);
  __syncthreads();
  // G2: ew2 -> ef -> bufIn chunks 0..15; rewrite extras (chunks 16,17) for mw1
  #pragma unroll
  for (int et=0;et<4;et++){ acc[et][0]=z; acc[et][1]=z; }
  gemm_rm<4,16>(bufA, wfrag + 20480, wu, lane, acc);
  epi_rm<24,false,true>(bufIn, acc, eb2, wu, lane);
  if (t < 64){
    float am = 0.25f*(attn_s[t*4]+attn_s[t*4+1]+attn_s[t*4+2]+attn_s[t*4+3]);
    pack8(&bufIn[lidx(t,16,24)],
          make_float4(am, rp_s[t*3+0], rp_s[t*3+1], rp_s[t*3+2]),
          make_float4(xnr_s[t*3+0], xnr_s[t*3+1], xnr_s[t*3+2], xnc_s[t*3+0]));
    pack8(&bufIn[lidx(t,17,24)],
          make_float4(xnc_s[t*3+1], xnc_s[t*3+2], 0.f, 0.f),
          make_float4(0.f,0.f,0.f,0.f));
  }
  __syncthreads();
  // G3: mw1 (KC=5) -> silu -> bufA
  #pragma unroll
  for (int et=0;et<4;et++){ acc[et][0]=z; acc[et][1]=z; }
  gemm_rm<5,24>(bufIn, wfrag + 36864, wu, lane, acc);
  epi_rm<16,true,true>(bufA, acc, mb1, wu, lane);
  __syncthreads();
  // G4: mw2 -> msgs(+mb2) -> bufIn chunks 0..15
  #pragma unroll
  for (int et=0;et<4;et++){ acc[et][0]=z; acc[et][1]=z; }
  gemm_rm<4,16>(bufA, wfrag + 57344, wu, lane, acc);
  epi_rm<24,false,true>(bufIn, acc, mb2, wu, lane);
  __syncthreads();
  // gates head dots via MFMA (reads bufIn only; concurrent reads OK)
  mfma_head<24>(bufIn, whfrag + 2048, wu, lane, g_s);
  // G5+G6: cw1 & xw1 from msgs (share B loads)
  f4v ax[4][2];
  #pragma unroll
  for (int et=0;et<4;et++){ acc[et][0]=z; acc[et][1]=z; ax[et][0]=z; ax[et][1]=z; }
  {
    const unsigned short* wfc = wfrag + 73728;
    const unsigned short* wfx = wfrag + 90112;
    int le = lane&15, quad = lane>>4;
    #pragma unroll
    for (int kc=0;kc<4;kc++){
      bf16x8 ac0 = *(const bf16x8*)(wfc + (((wu*2  )*4 + kc)<<9) + lane*8);
      bf16x8 ac1 = *(const bf16x8*)(wfc + (((wu*2+1)*4 + kc)<<9) + lane*8);
      bf16x8 ax0 = *(const bf16x8*)(wfx + (((wu*2  )*4 + kc)<<9) + lane*8);
      bf16x8 ax1 = *(const bf16x8*)(wfx + (((wu*2+1)*4 + kc)<<9) + lane*8);
      int chunk = kc*4 + quad;
      #pragma unroll
      for (int et=0;et<4;et++){
        bf16x8 b = *(const bf16x8*)(bufIn + lidx(et*16+le, chunk, 24));
        acc[et][0] = __builtin_amdgcn_mfma_f32_16x16x32_bf16(ac0, b, acc[et][0], 0,0,0);
        acc[et][1] = __builtin_amdgcn_mfma_f32_16x16x32_bf16(ac1, b, acc[et][1], 0,0,0);
        ax[et][0]  = __builtin_amdgcn_mfma_f32_16x16x32_bf16(ax0, b, ax[et][0], 0,0,0);
        ax[et][1]  = __builtin_amdgcn_mfma_f32_16x16x32_bf16(ax1, b, ax[et][1], 0,0,0);
      }
    }
  }
  __syncthreads();   // all waves done reading bufA (G4) & bufIn (G5/6 + gates)
  epi_rm<16,true,true>(bufA, acc, cb1, wu, lane);   // silu(cpre+cb1)
  __syncthreads();
  mfma_head<16>(bufA, whfrag + 4096, wu, lane, c_s);
  __syncthreads();
  epi_rm<16,true,true>(bufA, ax, xb1, wu, lane);    // silu(xpre+xb1)
  __syncthreads();
  mfma_head<16>(bufA, whfrag + 6144, wu, lane, xx_s);
  __syncthreads();
  // combine heads: shfl reduction over the 4 consecutive lanes of each edge group
  {
    int e2 = t>>2; int hh = t&3;
    float g = 1.0f/(1.0f+__expf(-(g_s[hh*65+e2]+gb[hh])));
    float cwv = c_s[hh*65+e2]+cb2[hh];
    float sv = g*cwv*coordw[hh];
    float csv = xx_s[hh*65+e2]+xb2[hh];
    sv += __shfl_xor(sv,1);  sv += __shfl_xor(sv,2);
    csv += __shfl_xor(csv,1); csv += __shfl_xor(csv,2);
    if (hh==0){ s_s[e2]=sv; cs_s[e2]=csv; }
  }
  __syncthreads();
  if (t < 64){
    int ge = ebase + t;
    float rp0=rp_s[t*3],rp1=rp_s[t*3+1],rp2=rp_s[t*3+2];
    float pp0,pp1,pp2;
    if (t > 0){ pp0=rp_s[(t-1)*3]; pp1=rp_s[(t-1)*3+1]; pp2=rp_s[(t-1)*3+2]; }
    else {
      int gp = (ebase==0)? (NE-1) : (ebase-1);
      int rr=ei[gp], cc2=ei[NE+gp];
      pp0=x[rr*3]-x[cc2*3]; pp1=x[rr*3+1]-x[cc2*3+1]; pp2=x[rr*3+2]-x[cc2*3+2];
    }
    float cv0 = rp1*pp2 - rp2*pp1;
    float cv1 = rp2*pp0 - rp0*pp2;
    float cv2 = rp0*pp1 - rp1*pp0;
    float sv = s_s[t], csv = cs_s[t];
    const float inv = 1.0f/49999.0f;
    cvec[(size_t)ge*3+0] = (sv*(0.9f*rp0+0.1f*xc_s[t*3+0]) + csv*cv0)*inv;
    cvec[(size_t)ge*3+1] = (sv*(0.9f*rp1+0.1f*xc_s[t*3+1]) + csv*cv1)*inv;
    cvec[(size_t)ge*3+2] = (sv*(0.9f*rp2+0.1f*xc_s[t*3+2]) + csv*cv2)*inv;
  }
}

// ---------------- fused aggregation + out GEMM: one wave per node ----------------
__global__ __launch_bounds__(256) void k_aggout(
    const int* __restrict__ ei, const int* __restrict__ offs, const int* __restrict__ elist,
    const float* __restrict__ eattn, const unsigned short* __restrict__ vb,
    const float* __restrict__ cvec, const float* __restrict__ Wo, const float* __restrict__ bo,
    float* __restrict__ outp){
  __shared__ float wvs[4*256];
  int t = threadIdx.x; int lane = t & 63; int w = t >> 6;
  int node = blockIdx.x*4 + w;
  const int* colp = ei + NE;
  int s0 = offs[node], s1 = offs[node+1];
  float a0=0,a1=0,a2=0,a3=0,cc=0;
  int i = s0;
  for (; i+4<=s1; i+=4){
    int e0=elist[i], e1=elist[i+1], e2=elist[i+2], e3=elist[i+3];
    int c0=colp[e0], c1=colp[e1], c2=colp[e2], c3=colp[e3];
    uint2 v0 = *(const uint2*)(vb + (size_t)c0*256 + lane*4);
    uint2 v1 = *(const uint2*)(vb + (size_t)c1*256 + lane*4);
    uint2 v2 = *(const uint2*)(vb + (size_t)c2*256 + lane*4);
    uint2 v3 = *(const uint2*)(vb + (size_t)c3*256 + lane*4);
    float4 at0 = *(const float4*)(eattn + (size_t)e0*4);
    float4 at1 = *(const float4*)(eattn + (size_t)e1*4);
    float4 at2 = *(const float4*)(eattn + (size_t)e2*4);
    float4 at3 = *(const float4*)(eattn + (size_t)e3*4);
    if (lane < 3) cc += cvec[(size_t)e0*3+lane] + cvec[(size_t)e1*3+lane]
                      + cvec[(size_t)e2*3+lane] + cvec[(size_t)e3*3+lane];
    a0 += at0.x*bf2f(v0.x&0xffffu) + at1.x*bf2f(v1.x&0xffffu) + at2.x*bf2f(v2.x&0xffffu) + at3.x*bf2f(v3.x&0xffffu);
    a1 += at0.y*bf2f(v0.x>>16)     + at1.y*bf2f(v1.x>>16)     + at2.y*bf2f(v2.x>>16)     + at3.y*bf2f(v3.x>>16);
    a2 += at0.z*bf2f(v0.y&0xffffu) + at1.z*bf2f(v1.y&0xffffu) + at2.z*bf2f(v2.y&0xffffu) + at3.z*bf2f(v3.y&0xffffu);
    a3 += at0.w*bf2f(v0.y>>16)     + at1.w*bf2f(v1.y>>16)     + at2.w*bf2f(v2.y>>16)     + at3.w*bf2f(v3.y>>16);
  }
  for (; i<s1; i++){
    int e0 = elist[i];
    int c0 = colp[e0];
    uint2 v0 = *(const uint2*)(vb + (size_t)c0*256 + lane*4);
    float4 at0 = *(const float4*)(eattn + (size_t)e0*4);
    if (lane < 3) cc += cvec[(size_t)e0*3+lane];
    a0 += at0.x*bf2f(v0.x&0xffffu);
    a1 += at0.y*bf2f(v0.x>>16);
    a2 += at0.z*bf2f(v0.y&0xffffu);
    a3 += at0.w*bf2f(v0.y>>16);
  }
  wvs[w*256 +       lane]=a0;
  wvs[w*256 +  64 + lane]=a1;
  wvs[w*256 + 128 + lane]=a2;
  wvs[w*256 + 192 + lane]=a3;
  if (lane < 3) outp[(size_t)NN*64 + (size_t)node*3 + lane] = cc;
  float o = bo[lane];
  #pragma unroll 4
  for (int k2=0;k2<256;k2++) o += wvs[w*256+k2] * Wo[k2*64+lane];
  outp[(size_t)node*64 + lane] = o;
}

extern "C" void kernel_launch(void* const* d_in, const int* in_sizes, int n_in,
                              void* d_out, int out_size, void* d_ws, size_t ws_size,
                              hipStream_t stream) {
  const float* h  = (const float*)d_in[0];
  const float* x  = (const float*)d_in[1];
  const int*   ei = (const int*)d_in[2];
  // d_in[3] = mask (all true)
  const float* Wq=(const float*)d_in[4];  const float* bq=(const float*)d_in[5];
  const float* Wk=(const float*)d_in[6];  const float* bk=(const float*)d_in[7];
  const float* Wv=(const float*)d_in[8];  const float* bv=(const float*)d_in[9];
  const float* Wo=(const float*)d_in[10]; const float* bo=(const float*)d_in[11];
  const float* pw1=(const float*)d_in[12]; const float* pb1=(const float*)d_in[13];
  const float* pw2=(const float*)d_in[14]; const float* pb2=(const float*)d_in[15];
  const float* ew1=(const float*)d_in[16]; const float* eb1=(const float*)d_in[17];
  const float* ew2=(const float*)d_in[18]; const float* eb2=(const float*)d_in[19];
  const float* eww=(const float*)d_in[20]; const float* ewb=(const float*)d_in[21];
  const float* mw1=(const float*)d_in[22]; const float* mb1=(const float*)d_in[23];
  const float* mw2=(const float*)d_in[24]; const float* mb2=(const float*)d_in[25];
  const float* gw=(const float*)d_in[26];  const float* gb=(const float*)d_in[27];
  const float* cw1=(const float*)d_in[28]; const float* cb1=(const float*)d_in[29];
  const float* cw2=(const float*)d_in[30]; const float* cb2=(const float*)d_in[31];
  const float* coordw=(const float*)d_in[32];
  const float* xw1=(const float*)d_in[33]; const float* xb1=(const float*)d_in[34];
  const float* xw2=(const float*)d_in[35]; const float* xb2=(const float*)d_in[36];

  // workspace layout (bytes), high-water = 103,829,472
  char* B = (char*)d_ws;
  float* eattn = (float*)(B + 0);                        // E*4*4   = 12,800,000
  float* cvec  = (float*)(B + 12800000);                 // E*3*4   =  9,600,000
  float* stats = (float*)(B + 22400000);                 // 64
  float* asum  = (float*)(B + 22400064);                 // N*4*4   =    800,000
  int* counts  = (int*)(B + 23200064);                   // N*4     =    200,000  (also cursor)
  int* offs    = (int*)(B + 23400064);                   // (N+1)*4 =    200,004
  unsigned short* wfrag = (unsigned short*)(B + 23600080); // 106,496 bf16 = 212,992
  int* elist   = (int*)(B + 23813088);                   // E*4     =  3,200,000
  unsigned short* qb = (unsigned short*)(B + 27013088);  // N*256*2 = 25,600,000
  unsigned short* kb = (unsigned short*)(B + 52613088);  // N*256*2 = 25,600,000
  unsigned short* vb = (unsigned short*)(B + 78213088);  // N*256*2 = 25,600,000
  unsigned short* whfrag = (unsigned short*)(B + 103813088); // 4*2048 bf16 = 16,384

  // zero stats+asum+counts (contiguous 1,000,064 B)
  k_zero<<<977,256,0,stream>>>(stats, 250016);
  // weight fragment prep (bf16, MFMA A-frag layout)
  k_wprep<<<80,256,0,stream>>>(ew1, wfrag + 0,     135, 5);
  k_wprep<<<64,256,0,stream>>>(ew2, wfrag + 20480, 128, 4);
  k_wprep<<<80,256,0,stream>>>(mw1, wfrag + 36864, 138, 5);
  k_wprep<<<64,256,0,stream>>>(mw2, wfrag + 57344, 128, 4);
  k_wprep<<<64,256,0,stream>>>(cw1, wfrag + 73728, 128, 4);
  k_wprep<<<64,256,0,stream>>>(xw1, wfrag + 90112, 128, 4);
  // head matrices [128][4] -> A-frags (M padded to 16)
  k_wprep4<<<8,256,0,stream>>>(eww, whfrag + 0);
  k_wprep4<<<8,256,0,stream>>>(gw,  whfrag + 2048);
  k_wprep4<<<8,256,0,stream>>>(cw2, whfrag + 4096);
  k_wprep4<<<8,256,0,stream>>>(xw2, whfrag + 6144);

  k_stats<<<196,256,0,stream>>>(x, stats);
  k_statsfin<<<1,64,0,stream>>>(stats);
  k_qkv<<<dim3(1563,12),256,0,stream>>>(h,Wq,bq,Wk,bk,Wv,bv,qb,kb,vb);
  k_count<<<3125,256,0,stream>>>(ei,counts);
  k_scan<<<1,256,0,stream>>>(counts,offs);
  k_fill<<<3125,256,0,stream>>>(ei,counts,elist);
  k_e1<<<12500,256,0,stream>>>(h,x,ei,stats,qb,kb,wfrag,whfrag,eb1,eb2,ewb,pw1,pb1,pw2,pb2,asum,eattn);
  k_e2<<<12500,256,0,stream>>>(h,x,ei,stats,asum,eattn,wfrag,whfrag,eb1,eb2,mb1,mb2,gb,cb1,cb2,coordw,xb1,xb2,cvec);
  k_aggout<<<12500,256,0,stream>>>(ei,offs,elist,eattn,vb,cvec,Wo,bo,(float*)d_out);
}

// Round 10
// 1664.746 us; speedup vs baseline: 1.2179x; 1.0497x over previous
//
#include <hip/hip_runtime.h>
#include <hip/hip_bf16.h>

#define NN 50000
#define NE 800000

typedef __bf16 bf16x8 __attribute__((ext_vector_type(8)));
typedef float f4v __attribute__((ext_vector_type(4)));

__device__ __forceinline__ float silu_f(float v){ return v/(1.0f+__expf(-v)); }
__device__ __forceinline__ float bf2f(unsigned int u){ return __uint_as_float(u<<16); }
// fast RNE bf16 round (finite inputs): identical result to __float2bfloat16 for non-NaN
__device__ __forceinline__ unsigned bfr(float f){
  unsigned b = __float_as_uint(f);
  return b + 0x7fffu + ((b>>16)&1u);
}
__device__ __forceinline__ unsigned short f2bf(float f){ return (unsigned short)(bfr(f)>>16); }
// pack two bf16 (low=a, high=b) with one v_perm_b32
__device__ __forceinline__ unsigned pk2(float a, float b){
  return __builtin_amdgcn_perm(bfr(b), bfr(a), 0x07060302u);
}

union U8 { unsigned short us[8]; uint4 u4; };

__device__ __forceinline__ void pack8(unsigned short* dst, float4 a, float4 b){
  uint4 u;
  u.x = pk2(a.x,a.y); u.y = pk2(a.z,a.w);
  u.z = pk2(b.x,b.y); u.w = pk2(b.z,b.w);
  *(uint4*)dst = u;
}

// short-index of 16B chunk c of row e in a row-major swizzled activation buffer
// (CH = chunks per row, multiple of 8; chunk swizzled within its group of 8)
__device__ __forceinline__ int lidx(int e, int c, int CH){
  return (e*CH + ((c & ~7) | ((c ^ e) & 7))) << 3;
}

// GEMM: A = weights (global frag order), B = activations (row-major swizzled LDS).
// acc[et][ot]: D rows = outcols (wu*32+ot*16+quad*4+r), cols = edges (et*16+(lane&15)).
template<int KC, int CH>
__device__ __forceinline__ void gemm_rm(const unsigned short* act, const unsigned short* wf,
                                        int wu, int lane, f4v (&acc)[4][2]){
  int le = lane & 15, quad = lane >> 4;
  #pragma unroll
  for (int kc=0;kc<KC;kc++){
    bf16x8 a0 = *(const bf16x8*)(wf + (((wu*2  )*KC + kc)<<9) + lane*8);
    bf16x8 a1 = *(const bf16x8*)(wf + (((wu*2+1)*KC + kc)<<9) + lane*8);
    int chunk = kc*4 + quad;
    #pragma unroll
    for (int et=0;et<4;et++){
      bf16x8 b = *(const bf16x8*)(act + lidx(et*16+le, chunk, CH));
      acc[et][0] = __builtin_amdgcn_mfma_f32_16x16x32_bf16(a0, b, acc[et][0], 0,0,0);
      acc[et][1] = __builtin_amdgcn_mfma_f32_16x16x32_bf16(a1, b, acc[et][1], 0,0,0);
    }
  }
}

// epilogue: D regs -> row-major swizzled bf16 buffer, packed b64 stores
template<int CH, bool SILU, bool BIAS>
__device__ __forceinline__ void epi_rm(unsigned short* dst, const f4v (&acc)[4][2],
                                       const float* bias, int wu, int lane){
  int le = lane & 15, quad = lane >> 4;
  #pragma unroll
  for (int ot=0; ot<2; ot++){
    float4 bv = make_float4(0,0,0,0);
    if (BIAS) bv = *(const float4*)(bias + wu*32 + ot*16 + quad*4);
    int chunk = wu*4 + ot*2 + (quad>>1);
    int soff = (quad&1)*4;
    #pragma unroll
    for (int et=0; et<4; et++){
      float v0=acc[et][ot][0], v1=acc[et][ot][1], v2=acc[et][ot][2], v3=acc[et][ot][3];
      if (BIAS){ v0+=bv.x; v1+=bv.y; v2+=bv.z; v3+=bv.w; }
      if (SILU){ v0=silu_f(v0); v1=silu_f(v1); v2=silu_f(v2); v3=silu_f(v3); }
      uint2 u; u.x = pk2(v0,v1); u.y = pk2(v2,v3);
      *(uint2*)(dst + lidx(et*16+le, chunk, CH) + soff) = u;
    }
  }
}

// head reduction as MFMA: out[h][e] = sum_k W[k][h]*act[e][k], h=0..3 (padded to 16).
// Wave wu covers edges wu*16..wu*16+15. whf = [KC=4][512] A-frag of W^T.
// D: row=quad*4+r -> head (rows 0..3 live in quad 0), col=le -> edge.
template<int CH>
__device__ __forceinline__ void mfma_head(const unsigned short* buf, const unsigned short* whf,
                                          int wu, int lane, float* dst /*[4*65]*/){
  int le = lane & 15, quad = lane >> 4;
  f4v hacc = {0.f,0.f,0.f,0.f};
  #pragma unroll
  for (int kc=0;kc<4;kc++){
    bf16x8 a = *(const bf16x8*)(whf + (kc<<9) + lane*8);
    bf16x8 b = *(const bf16x8*)(buf + lidx(wu*16+le, kc*4+quad, CH));
    hacc = __builtin_amdgcn_mfma_f32_16x16x32_bf16(a, b, hacc, 0,0,0);
  }
  if (quad==0){
    #pragma unroll
    for (int r=0;r<4;r++) dst[r*65 + wu*16 + le] = hacc[r];
  }
}

// ---------------- zero a span ----------------
__global__ __launch_bounds__(256) void k_zero(float* __restrict__ p, int n){
  int i = blockIdx.x*256 + threadIdx.x;
  if (i < n) p[i] = 0.f;
}

// ---------------- weight pre-pack into MFMA fragment order (bf16) ----------------
__global__ __launch_bounds__(256) void k_wprep(const float* __restrict__ src, unsigned short* __restrict__ dst,
                                               int Kreal, int KC){
  int idx = blockIdx.x*256 + threadIdx.x;
  int tot = 8*KC*512;
  if (idx >= tot) return;
  int nt  = idx/(KC*512); int rem = idx%(KC*512);
  int kc  = rem>>9;       int r2  = rem&511;
  int lq  = r2>>3;        int j   = r2&7;
  int k   = kc*32 + (lq>>4)*8 + j;
  int n   = nt*16 + (lq&15);
  float v = (k < Kreal) ? src[k*128 + n] : 0.f;
  dst[idx] = f2bf(v);
}

// head-matrix [128][4] -> A-frag (M padded 4->16), KC=4, 2048 shorts
__global__ __launch_bounds__(256) void k_wprep4(const float* __restrict__ src, unsigned short* __restrict__ dst){
  int idx = blockIdx.x*256 + threadIdx.x;
  if (idx >= 2048) return;
  int kc = idx>>9; int r2 = idx&511; int lq = r2>>3; int j = r2&7;
  int k = kc*32 + (lq>>4)*8 + j;
  int n = lq&15;
  dst[idx] = f2bf((n<4) ? src[k*4+n] : 0.f);
}

// ---------------- stats ----------------
__global__ __launch_bounds__(256) void k_stats(const float* __restrict__ x, float* __restrict__ stats){
  int i = blockIdx.x*256 + threadIdx.x;
  float v0=0.f,v1=0.f,v2=0.f;
  if (i < NN){ v0=x[i*3+0]; v1=x[i*3+1]; v2=x[i*3+2]; }
  float vals[6] = {v0,v1,v2,v0*v0,v1*v1,v2*v2};
  __shared__ float red[256];
  for (int c=0;c<6;c++){
    red[threadIdx.x]=vals[c];
    __syncthreads();
    for (int off=128; off>0; off>>=1){
      if (threadIdx.x < off) red[threadIdx.x] += red[threadIdx.x+off];
      __syncthreads();
    }
    if (threadIdx.x==0) atomicAdd(&stats[c], red[0]);
    __syncthreads();
  }
}

__global__ __launch_bounds__(64) void k_statsfin(float* __restrict__ stats){
  int t = threadIdx.x;
  if (t < 3){
    float s = stats[t], sq = stats[3+t];
    float mean = s/(float)NN;
    float var = (sq - s*s/(float)NN)/(float)(NN-1);
    float sd = sqrtf(var);
    stats[6+t] = mean;
    stats[9+t] = 1.0f/(sd + 1e-8f);
  }
}

// ---------------- q,k,v = h @ W + b  (bf16 out; v stored [node][d][head]) ----------------
__global__ __launch_bounds__(256) void k_qkv(const float* __restrict__ h,
    const float* __restrict__ Wq, const float* __restrict__ bq,
    const float* __restrict__ Wk, const float* __restrict__ bk,
    const float* __restrict__ Wv, const float* __restrict__ bv,
    unsigned short* __restrict__ q, unsigned short* __restrict__ kk, unsigned short* __restrict__ v){
  __shared__ float hs[32*68];
  int t = threadIdx.x;
  int by = blockIdx.y;
  int mat = by>>2; int quarter = by&3; int colbase = quarter*64;
  const float* W; const float* bb; unsigned short* outp;
  if (mat==0){W=Wq;bb=bq;outp=q;} else if (mat==1){W=Wk;bb=bk;outp=kk;} else {W=Wv;bb=bv;outp=v;}
  int r0 = blockIdx.x*32;
  {
    int rw = t>>3; int c0 = (t&7)*8;
    int row = r0 + rw;
    float4 a = make_float4(0,0,0,0), b2 = make_float4(0,0,0,0);
    if (row < NN){
      a  = *(const float4*)(h + (size_t)row*64 + c0);
      b2 = *(const float4*)(h + (size_t)row*64 + c0 + 4);
    }
    *(float4*)(&hs[rw*68 + c0])     = a;
    *(float4*)(&hs[rw*68 + c0 + 4]) = b2;
  }
  __syncthreads();
  int rg = t>>3; int cg = t&7; int col = colbase + cg*8;
  float acc[8];
  #pragma unroll
  for (int j=0;j<8;j++) acc[j]=0.f;
  for (int k2=0;k2<64;k2++){
    float a = hs[rg*68 + k2];
    const float4 w0 = *(const float4*)(W + k2*256 + col);
    const float4 w1 = *(const float4*)(W + k2*256 + col + 4);
    acc[0]+=a*w0.x; acc[1]+=a*w0.y; acc[2]+=a*w0.z; acc[3]+=a*w0.w;
    acc[4]+=a*w1.x; acc[5]+=a*w1.y; acc[6]+=a*w1.z; acc[7]+=a*w1.w;
  }
  int row = r0 + rg;
  if (row < NN){
    if (mat==2){
      #pragma unroll
      for (int j=0;j<8;j++) outp[(size_t)row*256 + (size_t)(cg*8+j)*4 + quarter] = f2bf(acc[j]+bb[col+j]);
    } else {
      U8 u;
      #pragma unroll
      for (int j=0;j<8;j++) u.us[j] = f2bf(acc[j]+bb[col+j]);
      *(uint4*)(outp + (size_t)row*256 + col) = u.u4;
    }
  }
}

// ---------------- CSR build ----------------
__global__ __launch_bounds__(256) void k_count(const int* __restrict__ ei, int* __restrict__ counts){
  int e = blockIdx.x*256 + threadIdx.x;
  if (e < NE) atomicAdd(&counts[ei[e]], 1);
}

__global__ __launch_bounds__(256) void k_scan(int* __restrict__ counts, int* __restrict__ offs){
  __shared__ int ps[256];
  int t = threadIdx.x;
  int base = t*196;
  int s = 0;
  for (int i=0;i<196;i++){ int idx = base+i; if (idx < NN) s += counts[idx]; }
  ps[t]=s; __syncthreads();
  for (int off=1; off<256; off<<=1){
    int vv = (t>=off)? ps[t-off] : 0;
    __syncthreads();
    ps[t]+=vv;
    __syncthreads();
  }
  int run = ps[t]-s;
  for (int i=0;i<196;i++){
    int idx = base+i;
    if (idx < NN){ int c = counts[idx]; offs[idx]=run; counts[idx]=run; run+=c; }
  }
  if (t==255) offs[NN]=run;
}

__global__ __launch_bounds__(256) void k_fill(const int* __restrict__ ei, int* __restrict__ cursor, int* __restrict__ elist){
  int e = blockIdx.x*256 + threadIdx.x;
  if (e < NE){
    int r = ei[e];
    int p = atomicAdd(&cursor[r],1);
    elist[p] = e;
  }
}

// ---------------- E1: edge MLP (MFMA, row-major LDS) + attention logits ----------------
__global__ __launch_bounds__(256) void k_e1(
    const float* __restrict__ h, const float* __restrict__ x, const int* __restrict__ ei,
    const float* __restrict__ stats,
    const unsigned short* __restrict__ qb, const unsigned short* __restrict__ kb,
    const unsigned short* __restrict__ wfrag, const unsigned short* __restrict__ whfrag,
    const float* __restrict__ eb1, const float* __restrict__ eb2,
    const float* __restrict__ ewb,
    const float* __restrict__ pw1, const float* __restrict__ pb1,
    const float* __restrict__ pw2, const float* __restrict__ pb2,
    float* __restrict__ asum, float* __restrict__ eattn){
  __shared__ __align__(16) unsigned short bufIn[64*24*8];  // K<=192 row-major swizzled
  __shared__ __align__(16) unsigned short bufA [64*16*8];  // K=128
  __shared__ float ewt_s[256], logit_s[256];
  __shared__ float ewt2_s[4*65];   // [h][e]: eww head dots (unique writer per slot)
  __shared__ float pp_s[4*260];    // [wave][h*65+e]: pos_enc partials, plain stores
  __shared__ float rd_s[64], xnr_s[192], xnc_s[192];
  __shared__ int row_s[64], col_s[64];
  int t = threadIdx.x; int lane = t & 63; int w = t >> 6;
  int wu = __builtin_amdgcn_readfirstlane(w);
  int ebase = blockIdx.x * 64;

  if (t < 64){
    int ge = ebase + t;
    int r = ei[ge], c = ei[NE+ge];
    row_s[t]=r; col_s[t]=c;
    float xr0=x[r*3],xr1=x[r*3+1],xr2=x[r*3+2];
    float xc0=x[c*3],xc1=x[c*3+1],xc2=x[c*3+2];
    float rp0=xr0-xc0, rp1=xr1-xc1, rp2=xr2-xc2;
    rd_s[t]=rp0*rp0+rp1*rp1+rp2*rp2;
    float m0=stats[6],m1=stats[7],m2=stats[8],s0=stats[9],s1=stats[10],s2=stats[11];
    xnr_s[t*3+0]=(xr0-m0)*s0; xnr_s[t*3+1]=(xr1-m1)*s1; xnr_s[t*3+2]=(xr2-m2)*s2;
    xnc_s[t*3+0]=(xc0-m0)*s0; xnc_s[t*3+1]=(xc1-m1)*s1; xnc_s[t*3+2]=(xc2-m2)*s2;
    #pragma unroll
    for (int hh=0;hh<4;hh++) ewt_s[t*4+hh] = ewb[hh] + pb2[hh];
  }
  __syncthreads();

  // q.k dots
  for (int ii=0; ii<16; ii++){
    int e = wu*16+ii;
    int r = row_s[e], c = col_s[e];
    uint2 qu = *(const uint2*)(qb + (size_t)r*256 + lane*4);
    uint2 ku = *(const uint2*)(kb + (size_t)c*256 + lane*4);
    float d = bf2f(qu.x&0xffffu)*bf2f(ku.x&0xffffu)
            + bf2f(qu.x>>16)   *bf2f(ku.x>>16)
            + bf2f(qu.y&0xffffu)*bf2f(ku.y&0xffffu)
            + bf2f(qu.y>>16)   *bf2f(ku.y>>16);
    d += __shfl_xor(d,1,16); d += __shfl_xor(d,2,16);
    d += __shfl_xor(d,4,16); d += __shfl_xor(d,8,16);
    if ((lane&15)==0) logit_s[e*4 + (lane>>4)] = d*0.125f;
  }
  // pos_enc partials: lane=edge, wave wu = j-slice; plain stores to wave-private region
  {
    int jb = wu*16;
    float rd = rd_s[lane];
    float p0=0,p1=0,p2=0,p3=0;
    for (int j=jb; j<jb+16; j++){
      float hp = rd*pw1[j] + pb1[j];
      float hs = silu_f(hp);
      const float4 w4 = *(const float4*)(pw2 + j*4);
      p0+=hs*w4.x; p1+=hs*w4.y; p2+=hs*w4.z; p3+=hs*w4.w;
    }
    float* pp = pp_s + wu*260;
    pp[0*65+lane]=p0; pp[1*65+lane]=p1; pp[2*65+lane]=p2; pp[3*65+lane]=p3;
  }
  // stage row-major: k 0..63 h[row], 64..127 h[col], 128..134 extras, rest zero
  {
    const float* hr = h + (size_t)row_s[lane]*64 + wu*16;
    pack8(&bufIn[lidx(lane, 2*wu,   24)], *(const float4*)(hr),   *(const float4*)(hr+4));
    pack8(&bufIn[lidx(lane, 2*wu+1, 24)], *(const float4*)(hr+8), *(const float4*)(hr+12));
    const float* hc = h + (size_t)col_s[lane]*64 + wu*16;
    pack8(&bufIn[lidx(lane, 8+2*wu, 24)], *(const float4*)(hc),   *(const float4*)(hc+4));
    pack8(&bufIn[lidx(lane, 9+2*wu, 24)], *(const float4*)(hc+8), *(const float4*)(hc+12));
  }
  if (t < 64){
    pack8(&bufIn[lidx(t,16,24)],
          make_float4(rd_s[t], xnr_s[t*3+0], xnr_s[t*3+1], xnr_s[t*3+2]),
          make_float4(xnc_s[t*3+0], xnc_s[t*3+1], xnc_s[t*3+2], 0.f));
  }
  {
    uint4 z4 = make_uint4(0,0,0,0);
    int e = t&63, j = t>>6;
    *(uint4*)&bufIn[lidx(e, 17+j, 24)] = z4;
    if (j < 3) *(uint4*)&bufIn[lidx(e, 21+j, 24)] = z4;
  }
  __syncthreads();
  f4v acc[4][2];
  f4v z = {0.f,0.f,0.f,0.f};
  // G1: ew1 (KC=5) -> silu(+eb1) -> bufA
  #pragma unroll
  for (int et=0;et<4;et++){ acc[et][0]=z; acc[et][1]=z; }
  gemm_rm<5,24>(bufIn, wfrag + 0, wu, lane, acc);
  epi_rm<16,true,true>(bufA, acc, eb1, wu, lane);
  __syncthreads();
  // G2: ew2 (KC=4) -> ef(+eb2) -> bufIn chunks 0..15
  #pragma unroll
  for (int et=0;et<4;et++){ acc[et][0]=z; acc[et][1]=z; }
  gemm_rm<4,16>(bufA, wfrag + 20480, wu, lane, acc);
  epi_rm<24,false,true>(bufIn, acc, eb2, wu, lane);
  __syncthreads();
  // eww head dots via MFMA (wave wu -> edges wu*16..+15, all 4 heads)
  mfma_head<24>(bufIn, whfrag + 0, wu, lane, ewt2_s);
  __syncthreads();
  {
    int e2 = t>>2, hh = t&3;
    float lg = logit_s[t] + ewt_s[t] + ewt2_s[hh*65+e2]
             + pp_s[0*260+hh*65+e2] + pp_s[1*260+hh*65+e2]
             + pp_s[2*260+hh*65+e2] + pp_s[3*260+hh*65+e2];
    float ex = __expf(lg);
    eattn[(size_t)ebase*4 + t] = ex;
    atomicAdd(&asum[row_s[e2]*4 + hh], ex);
  }
}

// ---------------- E2: recompute ef + message MLP + heads (MFMA, row-major LDS) ----------------
__global__ __launch_bounds__(256) void k_e2(
    const float* __restrict__ h, const float* __restrict__ x, const int* __restrict__ ei,
    const float* __restrict__ stats,
    const float* __restrict__ asum, float* __restrict__ eattn,
    const unsigned short* __restrict__ wfrag, const unsigned short* __restrict__ whfrag,
    const float* __restrict__ eb1, const float* __restrict__ eb2,
    const float* __restrict__ mb1, const float* __restrict__ mb2,
    const float* __restrict__ gb,
    const float* __restrict__ cb1, const float* __restrict__ cb2,
    const float* __restrict__ coordw,
    const float* __restrict__ xb1, const float* __restrict__ xb2,
    float* __restrict__ cvec){
  __shared__ __align__(16) unsigned short bufIn[64*24*8];
  __shared__ __align__(16) unsigned short bufA [64*16*8];
  __shared__ float attn_s[256];
  __shared__ float g_s[4*65], c_s[4*65], xx_s[4*65];   // [h][e], unique writer per slot
  __shared__ float s_s[64], cs_s[64];
  __shared__ float rp_s[192], rd_s[64], xnr_s[192], xnc_s[192], xc_s[192];
  __shared__ int row_s[64], col_s[64];
  int t = threadIdx.x; int lane = t & 63; int w = t >> 6;
  int wu = __builtin_amdgcn_readfirstlane(w);
  int ebase = blockIdx.x * 64;

  if (t < 64){
    int ge = ebase + t;
    int r = ei[ge], c = ei[NE+ge];
    row_s[t]=r; col_s[t]=c;
    float xr0=x[r*3],xr1=x[r*3+1],xr2=x[r*3+2];
    float xc0=x[c*3],xc1=x[c*3+1],xc2=x[c*3+2];
    float rp0=xr0-xc0, rp1=xr1-xc1, rp2=xr2-xc2;
    rp_s[t*3+0]=rp0; rp_s[t*3+1]=rp1; rp_s[t*3+2]=rp2;
    rd_s[t]=rp0*rp0+rp1*rp1+rp2*rp2;
    xc_s[t*3+0]=xc0; xc_s[t*3+1]=xc1; xc_s[t*3+2]=xc2;
    float m0=stats[6],m1=stats[7],m2=stats[8],s0=stats[9],s1=stats[10],s2=stats[11];
    xnr_s[t*3+0]=(xr0-m0)*s0; xnr_s[t*3+1]=(xr1-m1)*s1; xnr_s[t*3+2]=(xr2-m2)*s2;
    xnc_s[t*3+0]=(xc0-m0)*s0; xnc_s[t*3+1]=(xc1-m1)*s1; xnc_s[t*3+2]=(xc2-m2)*s2;
  }
  __syncthreads();
  // attn normalize (write back for k_aggout)
  {
    int e2 = t>>2; int hh = t&3;
    float ex = eattn[(size_t)ebase*4 + t];
    float a = ex / (asum[row_s[e2]*4 + hh] + 1e-8f);
    attn_s[t]=a;
    eattn[(size_t)ebase*4 + t]=a;
  }
  // stage row-major input (same as k_e1)
  {
    const float* hr = h + (size_t)row_s[lane]*64 + wu*16;
    pack8(&bufIn[lidx(lane, 2*wu,   24)], *(const float4*)(hr),   *(const float4*)(hr+4));
    pack8(&bufIn[lidx(lane, 2*wu+1, 24)], *(const float4*)(hr+8), *(const float4*)(hr+12));
    const float* hc = h + (size_t)col_s[lane]*64 + wu*16;
    pack8(&bufIn[lidx(lane, 8+2*wu, 24)], *(const float4*)(hc),   *(const float4*)(hc+4));
    pack8(&bufIn[lidx(lane, 9+2*wu, 24)], *(const float4*)(hc+8), *(const float4*)(hc+12));
  }
  if (t < 64){
    pack8(&bufIn[lidx(t,16,24)],
          make_float4(rd_s[t], xnr_s[t*3+0], xnr_s[t*3+1], xnr_s[t*3+2]),
          make_float4(xnc_s[t*3+0], xnc_s[t*3+1], xnc_s[t*3+2], 0.f));
  }
  {
    uint4 z4 = make_uint4(0,0,0,0);
    int e = t&63, j = t>>6;
    *(uint4*)&bufIn[lidx(e, 17+j, 24)] = z4;
    if (j < 3) *(uint4*)&bufIn[lidx(e, 21+j, 24)] = z4;
  }
  __syncthreads();
  f4v acc[4][2];
  f4v z = {0.f,0.f,0.f,0.f};
  // G1: ew1 -> silu -> bufA
  #pragma unroll
  for (int et=0;et<4;et++){ acc[et][0]=z; acc[et][1]=z; }
  gemm_rm<5,24>(bufIn, wfrag + 0, wu, lane, acc);
  epi_rm<16,true,true>(bufA, acc, eb1, wu, lane);
  __syncthreads();
  // G2: ew2 -> ef -> bufIn chunks 0..15; rewrite extras (chunks 16,17) for mw1
  #pragma unroll
  for (int et=0;et<4;et++){ acc[et][0]=z; acc[et][1]=z; }
  gemm_rm<4,16>(bufA, wfrag + 20480, wu, lane, acc);
  epi_rm<24,false,true>(bufIn, acc, eb2, wu, lane);
  if (t < 64){
    float am = 0.25f*(attn_s[t*4]+attn_s[t*4+1]+attn_s[t*4+2]+attn_s[t*4+3]);
    pack8(&bufIn[lidx(t,16,24)],
          make_float4(am, rp_s[t*3+0], rp_s[t*3+1], rp_s[t*3+2]),
          make_float4(xnr_s[t*3+0], xnr_s[t*3+1], xnr_s[t*3+2], xnc_s[t*3+0]));
    pack8(&bufIn[lidx(t,17,24)],
          make_float4(xnc_s[t*3+1], xnc_s[t*3+2], 0.f, 0.f),
          make_float4(0.f,0.f,0.f,0.f));
  }
  __syncthreads();
  // G3: mw1 (KC=5) -> silu -> bufA
  #pragma unroll
  for (int et=0;et<4;et++){ acc[et][0]=z; acc[et][1]=z; }
  gemm_rm<5,24>(bufIn, wfrag + 36864, wu, lane, acc);
  epi_rm<16,true,true>(bufA, acc, mb1, wu, lane);
  __syncthreads();
  // G4: mw2 -> msgs(+mb2) -> bufIn chunks 0..15
  #pragma unroll
  for (int et=0;et<4;et++){ acc[et][0]=z; acc[et][1]=z; }
  gemm_rm<4,16>(bufA, wfrag + 57344, wu, lane, acc);
  epi_rm<24,false,true>(bufIn, acc, mb2, wu, lane);
  __syncthreads();
  // gates head dots via MFMA (reads bufIn only; concurrent reads OK)
  mfma_head<24>(bufIn, whfrag + 2048, wu, lane, g_s);
  // G5+G6: cw1 & xw1 from msgs (share B loads)
  f4v ax[4][2];
  #pragma unroll
  for (int et=0;et<4;et++){ acc[et][0]=z; acc[et][1]=z; ax[et][0]=z; ax[et][1]=z; }
  {
    const unsigned short* wfc = wfrag + 73728;
    const unsigned short* wfx = wfrag + 90112;
    int le = lane&15, quad = lane>>4;
    #pragma unroll
    for (int kc=0;kc<4;kc++){
      bf16x8 ac0 = *(const bf16x8*)(wfc + (((wu*2  )*4 + kc)<<9) + lane*8);
      bf16x8 ac1 = *(const bf16x8*)(wfc + (((wu*2+1)*4 + kc)<<9) + lane*8);
      bf16x8 ax0 = *(const bf16x8*)(wfx + (((wu*2  )*4 + kc)<<9) + lane*8);
      bf16x8 ax1 = *(const bf16x8*)(wfx + (((wu*2+1)*4 + kc)<<9) + lane*8);
      int chunk = kc*4 + quad;
      #pragma unroll
      for (int et=0;et<4;et++){
        bf16x8 b = *(const bf16x8*)(bufIn + lidx(et*16+le, chunk, 24));
        acc[et][0] = __builtin_amdgcn_mfma_f32_16x16x32_bf16(ac0, b, acc[et][0], 0,0,0);
        acc[et][1] = __builtin_amdgcn_mfma_f32_16x16x32_bf16(ac1, b, acc[et][1], 0,0,0);
        ax[et][0]  = __builtin_amdgcn_mfma_f32_16x16x32_bf16(ax0, b, ax[et][0], 0,0,0);
        ax[et][1]  = __builtin_amdgcn_mfma_f32_16x16x32_bf16(ax1, b, ax[et][1], 0,0,0);
      }
    }
  }
  __syncthreads();   // all waves done reading bufA (G4) & bufIn (G5/6 + gates)
  epi_rm<16,true,true>(bufA, acc, cb1, wu, lane);   // silu(cpre+cb1)
  __syncthreads();
  mfma_head<16>(bufA, whfrag + 4096, wu, lane, c_s);
  __syncthreads();
  epi_rm<16,true,true>(bufA, ax, xb1, wu, lane);    // silu(xpre+xb1)
  __syncthreads();
  mfma_head<16>(bufA, whfrag + 6144, wu, lane, xx_s);
  __syncthreads();
  // combine heads: shfl reduction over the 4 consecutive lanes of each edge group
  {
    int e2 = t>>2; int hh = t&3;
    float g = 1.0f/(1.0f+__expf(-(g_s[hh*65+e2]+gb[hh])));
    float cwv = c_s[hh*65+e2]+cb2[hh];
    float sv = g*cwv*coordw[hh];
    float csv = xx_s[hh*65+e2]+xb2[hh];
    sv += __shfl_xor(sv,1);  sv += __shfl_xor(sv,2);
    csv += __shfl_xor(csv,1); csv += __shfl_xor(csv,2);
    if (hh==0){ s_s[e2]=sv; cs_s[e2]=csv; }
  }
  __syncthreads();
  if (t < 64){
    int ge = ebase + t;
    float rp0=rp_s[t*3],rp1=rp_s[t*3+1],rp2=rp_s[t*3+2];
    float pp0,pp1,pp2;
    if (t > 0){ pp0=rp_s[(t-1)*3]; pp1=rp_s[(t-1)*3+1]; pp2=rp_s[(t-1)*3+2]; }
    else {
      int gp = (ebase==0)? (NE-1) : (ebase-1);
      int rr=ei[gp], cc2=ei[NE+gp];
      pp0=x[rr*3]-x[cc2*3]; pp1=x[rr*3+1]-x[cc2*3+1]; pp2=x[rr*3+2]-x[cc2*3+2];
    }
    float cv0 = rp1*pp2 - rp2*pp1;
    float cv1 = rp2*pp0 - rp0*pp2;
    float cv2 = rp0*pp1 - rp1*pp0;
    float sv = s_s[t], csv = cs_s[t];
    const float inv = 1.0f/49999.0f;
    cvec[(size_t)ge*3+0] = (sv*(0.9f*rp0+0.1f*xc_s[t*3+0]) + csv*cv0)*inv;
    cvec[(size_t)ge*3+1] = (sv*(0.9f*rp1+0.1f*xc_s[t*3+1]) + csv*cv1)*inv;
    cvec[(size_t)ge*3+2] = (sv*(0.9f*rp2+0.1f*xc_s[t*3+2]) + csv*cv2)*inv;
  }
}

// ---------------- fused aggregation + out GEMM: one wave per node ----------------
__global__ __launch_bounds__(256) void k_aggout(
    const int* __restrict__ ei, const int* __restrict__ offs, const int* __restrict__ elist,
    const float* __restrict__ eattn, const unsigned short* __restrict__ vb,
    const float* __restrict__ cvec, const float* __restrict__ Wo, const float* __restrict__ bo,
    float* __restrict__ outp){
  __shared__ float wvs[4*256];
  int t = threadIdx.x; int lane = t & 63; int w = t >> 6;
  int node = blockIdx.x*4 + w;
  const int* colp = ei + NE;
  int s0 = offs[node], s1 = offs[node+1];
  float a0=0,a1=0,a2=0,a3=0,cc=0;
  int i = s0;
  for (; i+4<=s1; i+=4){
    int e0=elist[i], e1=elist[i+1], e2=elist[i+2], e3=elist[i+3];
    int c0=colp[e0], c1=colp[e1], c2=colp[e2], c3=colp[e3];
    uint2 v0 = *(const uint2*)(vb + (size_t)c0*256 + lane*4);
    uint2 v1 = *(const uint2*)(vb + (size_t)c1*256 + lane*4);
    uint2 v2 = *(const uint2*)(vb + (size_t)c2*256 + lane*4);
    uint2 v3 = *(const uint2*)(vb + (size_t)c3*256 + lane*4);
    float4 at0 = *(const float4*)(eattn + (size_t)e0*4);
    float4 at1 = *(const float4*)(eattn + (size_t)e1*4);
    float4 at2 = *(const float4*)(eattn + (size_t)e2*4);
    float4 at3 = *(const float4*)(eattn + (size_t)e3*4);
    if (lane < 3) cc += cvec[(size_t)e0*3+lane] + cvec[(size_t)e1*3+lane]
                      + cvec[(size_t)e2*3+lane] + cvec[(size_t)e3*3+lane];
    a0 += at0.x*bf2f(v0.x&0xffffu) + at1.x*bf2f(v1.x&0xffffu) + at2.x*bf2f(v2.x&0xffffu) + at3.x*bf2f(v3.x&0xffffu);
    a1 += at0.y*bf2f(v0.x>>16)     + at1.y*bf2f(v1.x>>16)     + at2.y*bf2f(v2.x>>16)     + at3.y*bf2f(v3.x>>16);
    a2 += at0.z*bf2f(v0.y&0xffffu) + at1.z*bf2f(v1.y&0xffffu) + at2.z*bf2f(v2.y&0xffffu) + at3.z*bf2f(v3.y&0xffffu);
    a3 += at0.w*bf2f(v0.y>>16)     + at1.w*bf2f(v1.y>>16)     + at2.w*bf2f(v2.y>>16)     + at3.w*bf2f(v3.y>>16);
  }
  for (; i<s1; i++){
    int e0 = elist[i];
    int c0 = colp[e0];
    uint2 v0 = *(const uint2*)(vb + (size_t)c0*256 + lane*4);
    float4 at0 = *(const float4*)(eattn + (size_t)e0*4);
    if (lane < 3) cc += cvec[(size_t)e0*3+lane];
    a0 += at0.x*bf2f(v0.x&0xffffu);
    a1 += at0.y*bf2f(v0.x>>16);
    a2 += at0.z*bf2f(v0.y&0xffffu);
    a3 += at0.w*bf2f(v0.y>>16);
  }
  wvs[w*256 +       lane]=a0;
  wvs[w*256 +  64 + lane]=a1;
  wvs[w*256 + 128 + lane]=a2;
  wvs[w*256 + 192 + lane]=a3;
  if (lane < 3) outp[(size_t)NN*64 + (size_t)node*3 + lane] = cc;
  float o = bo[lane];
  #pragma unroll 4
  for (int k2=0;k2<256;k2++) o += wvs[w*256+k2] * Wo[k2*64+lane];
  outp[(size_t)node*64 + lane] = o;
}

extern "C" void kernel_launch(void* const* d_in, const int* in_sizes, int n_in,
                              void* d_out, int out_size, void* d_ws, size_t ws_size,
                              hipStream_t stream) {
  const float* h  = (const float*)d_in[0];
  const float* x  = (const float*)d_in[1];
  const int*   ei = (const int*)d_in[2];
  // d_in[3] = mask (all true)
  const float* Wq=(const float*)d_in[4];  const float* bq=(const float*)d_in[5];
  const float* Wk=(const float*)d_in[6];  const float* bk=(const float*)d_in[7];
  const float* Wv=(const float*)d_in[8];  const float* bv=(const float*)d_in[9];
  const float* Wo=(const float*)d_in[10]; const float* bo=(const float*)d_in[11];
  const float* pw1=(const float*)d_in[12]; const float* pb1=(const float*)d_in[13];
  const float* pw2=(const float*)d_in[14]; const float* pb2=(const float*)d_in[15];
  const float* ew1=(const float*)d_in[16]; const float* eb1=(const float*)d_in[17];
  const float* ew2=(const float*)d_in[18]; const float* eb2=(const float*)d_in[19];
  const float* eww=(const float*)d_in[20]; const float* ewb=(const float*)d_in[21];
  const float* mw1=(const float*)d_in[22]; const float* mb1=(const float*)d_in[23];
  const float* mw2=(const float*)d_in[24]; const float* mb2=(const float*)d_in[25];
  const float* gw=(const float*)d_in[26];  const float* gb=(const float*)d_in[27];
  const float* cw1=(const float*)d_in[28]; const float* cb1=(const float*)d_in[29];
  const float* cw2=(const float*)d_in[30]; const float* cb2=(const float*)d_in[31];
  const float* coordw=(const float*)d_in[32];
  const float* xw1=(const float*)d_in[33]; const float* xb1=(const float*)d_in[34];
  const float* xw2=(const float*)d_in[35]; const float* xb2=(const float*)d_in[36];

  // workspace layout (bytes), high-water = 103,829,472
  char* B = (char*)d_ws;
  float* eattn = (float*)(B + 0);                        // E*4*4   = 12,800,000
  float* cvec  = (float*)(B + 12800000);                 // E*3*4   =  9,600,000
  float* stats = (float*)(B + 22400000);                 // 64
  float* asum  = (float*)(B + 22400064);                 // N*4*4   =    800,000
  int* counts  = (int*)(B + 23200064);                   // N*4     =    200,000  (also cursor)
  int* offs    = (int*)(B + 23400064);                   // (N+1)*4 =    200,004
  unsigned short* wfrag = (unsigned short*)(B + 23600080); // 106,496 bf16 = 212,992
  int* elist   = (int*)(B + 23813088);                   // E*4     =  3,200,000
  unsigned short* qb = (unsigned short*)(B + 27013088);  // N*256*2 = 25,600,000
  unsigned short* kb = (unsigned short*)(B + 52613088);  // N*256*2 = 25,600,000
  unsigned short* vb = (unsigned short*)(B + 78213088);  // N*256*2 = 25,600,000
  unsigned short* whfrag = (unsigned short*)(B + 103813088); // 4*2048 bf16 = 16,384

  // zero stats+asum+counts (contiguous 1,000,064 B)
  k_zero<<<977,256,0,stream>>>(stats, 250016);
  // weight fragment prep (bf16, MFMA A-frag layout)
  k_wprep<<<80,256,0,stream>>>(ew1, wfrag + 0,     135, 5);
  k_wprep<<<64,256,0,stream>>>(ew2, wfrag + 20480, 128, 4);
  k_wprep<<<80,256,0,stream>>>(mw1, wfrag + 36864, 138, 5);
  k_wprep<<<64,256,0,stream>>>(mw2, wfrag + 57344, 128, 4);
  k_wprep<<<64,256,0,stream>>>(cw1, wfrag + 73728, 128, 4);
  k_wprep<<<64,256,0,stream>>>(xw1, wfrag + 90112, 128, 4);
  // head matrices [128][4] -> A-frags (M padded to 16)
  k_wprep4<<<8,256,0,stream>>>(eww, whfrag + 0);
  k_wprep4<<<8,256,0,stream>>>(gw,  whfrag + 2048);
  k_wprep4<<<8,256,0,stream>>>(cw2, whfrag + 4096);
  k_wprep4<<<8,256,0,stream>>>(xw2, whfrag + 6144);

  k_stats<<<196,256,0,stream>>>(x, stats);
  k_statsfin<<<1,64,0,stream>>>(stats);
  k_qkv<<<dim3(1563,12),256,0,stream>>>(h,Wq,bq,Wk,bk,Wv,bv,qb,kb,vb);
  k_count<<<3125,256,0,stream>>>(ei,counts);
  k_scan<<<1,256,0,stream>>>(counts,offs);
  k_fill<<<3125,256,0,stream>>>(ei,counts,elist);
  k_e1<<<12500,256,0,stream>>>(h,x,ei,stats,qb,kb,wfrag,whfrag,eb1,eb2,ewb,pw1,pb1,pw2,pb2,asum,eattn);
  k_e2<<<12500,256,0,stream>>>(h,x,ei,stats,asum,eattn,wfrag,whfrag,eb1,eb2,mb1,mb2,gb,cb1,cb2,coordw,xb1,xb2,cvec);
  k_aggout<<<12500,256,0,stream>>>(ei,offs,elist,eattn,vb,cvec,Wo,bo,(float*)d_out);
}